// Round 11
// baseline (844.529 us; speedup 1.0000x reference)
//
#include <hip/hip_runtime.h>

#define HDIM 192
#define EPS 1e-5f

typedef __attribute__((ext_vector_type(8))) _Float16 half8;
typedef __attribute__((ext_vector_type(4))) float floatx4;

__device__ __forceinline__ float h2f(ushort u) {
    union { ushort u; _Float16 h; } c; c.u = u; return (float)c.h;
}
__device__ __forceinline__ ushort f2h(float x) {
    _Float16 h = (_Float16)x;           // RTN
    union { _Float16 h; ushort u; } c; c.h = h; return c.u;
}
__device__ __forceinline__ uint4 pack8(const ushort* h) {
    uint4 p;
    p.x = h[0] | ((uint)h[1] << 16); p.y = h[2] | ((uint)h[3] << 16);
    p.z = h[4] | ((uint)h[5] << 16); p.w = h[6] | ((uint)h[7] << 16);
    return p;
}

// async global->LDS DMA, 16B per lane; LDS dest = wave-uniform base + lane*16,
// global source is PER-LANE (guide m104/m173).
__device__ __forceinline__ void gload_lds16(const ushort* g, ushort* l) {
    __builtin_amdgcn_global_load_lds(
        (const __attribute__((address_space(1))) unsigned int*)g,
        (__attribute__((address_space(3))) unsigned int*)l, 16, 0, 0);
}

#define WAITV0() asm volatile("s_waitcnt vmcnt(0)" ::: "memory")

// Activations are ROW-MAJOR fp16 [R][K].

// ---------------------------------------------------------------------------
// Merged weight prep: all 10 matrices in ONE launch.
// ---------------------------------------------------------------------------
struct PrepArgs {
    const float* src[6];
    ushort*      dst[6];
    int K[6];
    int off[7];       // thread offsets (per entry: nmat*(K/32)*12*64)
};

__global__ __launch_bounds__(256) void prep_all_k(PrepArgs a)
{
    int idx = blockIdx.x * 256 + threadIdx.x;
    if (idx >= a.off[6]) return;
    int i = 0;
    #pragma unroll
    for (int t = 1; t < 6; ++t) if (idx >= a.off[t]) i = t;
    int r = idx - a.off[i];
    int K = a.K[i];
    int perMat = (K >> 5) * 12 * 64;
    int mat = r / perMat;
    r -= mat * perMat;
    int lane = r & 63;
    int ct = (r >> 6) % 12;
    int kc = r / (12 * 64);
    int col = ct * 16 + (lane & 15);
    int kb  = kc * 32 + (lane >> 4) * 8;
    const float* Wm = a.src[i] + (size_t)mat * K * HDIM;
    ushort* base = a.dst[i] + (size_t)mat * K * HDIM;
    size_t o = (size_t)kc * 6144 + (size_t)(ct * 64 + lane) * 8;
    #pragma unroll
    for (int j = 0; j < 8; ++j)
        base[o + j] = f2h(Wm[(size_t)(kb + j) * HDIM + col]);
}

// ---------------------------------------------------------------------------
// fp32 row-major [R, C] -> fp16 row-major. One thread per 8 channels.
// ---------------------------------------------------------------------------
__global__ __launch_bounds__(256) void conv_half_k(
    const float* __restrict__ src, ushort* __restrict__ dst, int R, int C)
{
    int OC = C >> 3;
    int idx = blockIdx.x * 256 + threadIdx.x;
    if (idx >= R * OC) return;
    int r = idx / OC;
    int o = idx - r * OC;
    float4 v0 = ((const float4*)(src + (size_t)r * C + o * 8))[0];
    float4 v1 = ((const float4*)(src + (size_t)r * C + o * 8))[1];
    float v[8] = {v0.x, v0.y, v0.z, v0.w, v1.x, v1.y, v1.z, v1.w};
    ushort h[8];
    #pragma unroll
    for (int t = 0; t < 8; ++t) h[t] = f2h(v[t]);
    *(uint4*)(dst + (size_t)r * C + o * 8) = pack8(h);
}

// ---------------------------------------------------------------------------
// MFMA GEMM (layer0 + head): slab staging, barrier-free K-loop, LDS C-tile,
// per-block BN partials (no global atomics).  256 thr / 4 waves.
// ---------------------------------------------------------------------------
template<bool DUAL, bool RELU, bool DEG, bool STATS, int NKC>
__global__ __launch_bounds__(256, 3) void gemm_mfma_k(
    const ushort* __restrict__ A1h, const ushort* __restrict__ W1f,
    const ushort* __restrict__ A2h, const ushort* __restrict__ W2f,
    const float* __restrict__ degf, const float* __restrict__ bias,
    ushort* __restrict__ C, float* __restrict__ pstats, int N, int K)
{
    constexpr int KR   = NKC * 32;          // A row length (ushorts)
    constexpr int RS   = KR + 8;            // padded LDS row stride (ushorts)
    constexpr int SLAB = 64 * RS;           // ushorts per slab
    constexpr int NINSTR = SLAB / 512;      // wave DMA instrs per slab (1KB each)
    constexpr int NCH  = DUAL ? 2 * NKC : NKC;
    constexpr int SMEMU = ((DUAL ? 2 * SLAB : SLAB) > 12800)
                            ? (DUAL ? 2 * SLAB : SLAB) : 12800;  // C-tile needs 64*200

    __shared__ float sstat[2][HDIM];
    __shared__ __align__(16) ushort smem[SMEMU];
    const int tid  = threadIdx.x;
    const int wave = tid >> 6;      // 0..3 = column group (48 cols each)
    const int lane = tid & 63;
    const int row0 = blockIdx.x * 64;
    const int m16 = lane & 15;
    const int g4  = lane >> 4;

    if (STATS && tid < HDIM) { sstat[0][tid] = 0.f; sstat[1][tid] = 0.f; }

    // ---- slab staging: linear LDS slots -> per-lane (row, offset) source
    auto stage = [&](const ushort* Ab, int slabOff) {
        #pragma unroll
        for (int i = wave; i < NINSTR; i += 4) {
            int slotB = i * 1024 + lane * 16;        // byte offset in slab
            int r   = slotB / (RS * 2);
            int off = slotB - r * (RS * 2);          // byte within padded row
            if (off >= KR * 2) off = KR * 2 - 16;    // pad slot: dup last 16B
            int rr = row0 + r; if (rr >= N) rr = N - 1;
            gload_lds16(Ab + (size_t)rr * KR + (off >> 1),
                        smem + slabOff + i * 512);   // wave-uniform dest base
        }
    };

    stage(A1h, 0);
    if constexpr (DUAL) stage(A2h, SLAB);
    WAITV0();
    __builtin_amdgcn_s_barrier();            // all waves' slab quarters landed
    __builtin_amdgcn_sched_barrier(0);

    auto loadB = [&](int c, half8* b) {
        bool ph = DUAL && (c >= NKC);
        int kc = ph ? c - NKC : c;
        const ushort* Bp = (ph ? W2f : W1f) + (size_t)kc * 6144
                         + (size_t)(wave * 192 + lane) * 8;
        #pragma unroll
        for (int ct = 0; ct < 3; ++ct)
            b[ct] = *(const half8*)(Bp + ct * 512);
    };

    floatx4 acc[4][3];
    #pragma unroll
    for (int s = 0; s < 4; ++s)
        #pragma unroll
        for (int ct = 0; ct < 3; ++ct) acc[s][ct] = (floatx4){0.f, 0.f, 0.f, 0.f};

    // ---- K-loop: pure LDS + MFMA, no barriers, B register-dbuf from L2
    half8 bA[3], bB[3];
    loadB(0, bA);
    #pragma unroll
    for (int c = 0; c < NCH; ++c) {
        if (c + 1 < NCH) loadB(c + 1, (c & 1) ? bA : bB);
        const int base = (DUAL && c >= NKC) ? SLAB : 0;
        const int kc   = (DUAL && c >= NKC) ? c - NKC : c;
        const ushort* aB = smem + base + m16 * RS + kc * 32 + g4 * 8;
        half8 a[4];
        #pragma unroll
        for (int s = 0; s < 4; ++s)
            a[s] = *(const half8*)(aB + s * 16 * RS);
        const half8* bu = (c & 1) ? bB : bA;
        #pragma unroll
        for (int ct = 0; ct < 3; ++ct)
            #pragma unroll
            for (int s = 0; s < 4; ++s)
                acc[s][ct] = __builtin_amdgcn_mfma_f32_16x16x32_f16(a[s], bu[ct], acc[s][ct], 0, 0, 0);
    }

    // ---- epilogue: acc -> LDS C-tile (reuses slab0) -> linear global burst
    __syncthreads();                // all waves done reading slabs
    // C/D layout col=lane&15, row=(lane>>4)*4+reg  [m89]
    #pragma unroll
    for (int ct = 0; ct < 3; ++ct) {
        int col = wave * 48 + ct * 16 + m16;
        float bv = bias ? bias[col] : 0.f;
        float lsum = 0.f, lsq = 0.f;
        #pragma unroll
        for (int s = 0; s < 4; ++s) {
            #pragma unroll
            for (int reg = 0; reg < 4; ++reg) {
                int rloc = s * 16 + g4 * 4 + reg;
                int rr = row0 + rloc;
                int rrc = rr < N ? rr : N - 1;
                float v = acc[s][ct][reg] + (DEG ? degf[rrc] * bv : bv);
                if (STATS && rr < N) { lsum += v; lsq += v * v; }
                if (RELU) v = fmaxf(v, 0.f);
                smem[rloc * 200 + col] = f2h(v);
            }
        }
        if (STATS) {
            lsum += __shfl_xor(lsum, 16); lsum += __shfl_xor(lsum, 32);
            lsq  += __shfl_xor(lsq, 16);  lsq  += __shfl_xor(lsq, 32);
            if (g4 == 0) {
                atomicAdd(&sstat[0][col], lsum);   // LDS atomics: cheap
                atomicAdd(&sstat[1][col], lsq);
            }
        }
    }
    __syncthreads();                // C-tile + sstat complete
    {
        int rowsLeft = N - row0; if (rowsLeft > 64) rowsLeft = 64;
        int lim = rowsLeft * 24;    // uint4 count (24 per row)
        ushort* Cb = C + (size_t)row0 * HDIM;
        #pragma unroll
        for (int k = 0; k < 6; ++k) {
            int u = tid + k * 256;
            if (u < lim) {
                int r  = u / 24;
                int c8 = (u - r * 24) * 8;
                *(uint4*)(Cb + (size_t)u * 8) =
                    *(const uint4*)(smem + r * 200 + c8);
            }
        }
    }
    if (STATS) {
        if (tid < HDIM) {
            float* pb = pstats + (size_t)blockIdx.x * (2 * HDIM);
            pb[tid]        = sstat[0][tid];
            pb[HDIM + tid] = sstat[1][tid];
        }
    }
}

// ---------------------------------------------------------------------------
// FUSED layer kernel (layers 1..3), 512 thr / 8 waves, SINGLE-SLAB two-pass:
//  LDS = 1 slab (25.6KB) + sstat -> 27.1KB -> 4 blocks/CU (32 waves, 100%
//  wave occupancy; was 2 slabs/52.7KB/3 blocks/33% measured occupancy).
//  Sequence: stage own rows -> (BN coeffs under DMA) -> BN apply in LDS ->
//  GEMM PASS 1 acc += A2(own) x Wroot -> bar -> gather neighbors OVERWRITE
//  slab (A1) -> bar -> GEMM PASS 2 acc += A1 x Wrel -> epilogue.
//  Addition commutes, so two passes == old dual GEMM bit-for-bit per chunk
//  order (chunk order within each operand unchanged).
//  Output C MUST differ from Hraw (ping-pong).
// ---------------------------------------------------------------------------
__global__ __launch_bounds__(512, 8) void gemm_fused_k(
    const ushort* __restrict__ Hraw, const ushort* __restrict__ W1f,
    const ushort* __restrict__ W2f,
    const float* __restrict__ degf, const float* __restrict__ bias,
    const float* __restrict__ instats, const float* __restrict__ gammaL,
    const float* __restrict__ betaL, float invN,
    const int* __restrict__ row_ptr, const int* __restrict__ col,
    ushort* __restrict__ C, float* __restrict__ pstats, int N)
{
    constexpr int KR   = 192;
    constexpr int RS   = 200;               // padded row stride (ushorts)
    constexpr int SLAB = 64 * RS;           // 12800 ushorts = 25.6KB
    constexpr int NINSTR = SLAB / 512;      // 25 DMA instrs per slab
    constexpr int NKC  = 6;

    __shared__ float sstat[2][HDIM];
    __shared__ __align__(16) ushort smem[SLAB];
    const int tid  = threadIdx.x;
    const int wave = tid >> 6;              // 0..7
    const int lane = tid & 63;
    const int row0 = blockIdx.x * 64;
    const int m16 = lane & 15;
    const int g4  = lane >> 4;

    // ---- phase 1: stage own raw rows into the slab
    #pragma unroll
    for (int i = wave; i < NINSTR; i += 8) {
        int slotB = i * 1024 + lane * 16;
        int r   = slotB / (RS * 2);
        int off = slotB - r * (RS * 2);
        if (off >= KR * 2) off = KR * 2 - 16;
        int rr = row0 + r; if (rr >= N) rr = N - 1;
        gload_lds16(Hraw + (size_t)rr * KR + (off >> 1),
                    smem + i * 512);
    }
    // BN coeffs computed while the DMA is in flight (only needs instats)
    if (tid < HDIM) {
        float mu  = instats[tid] * invN;
        float var = instats[HDIM + tid] * invN - mu * mu;
        float s = gammaL[tid] * rsqrtf(var + EPS);
        sstat[0][tid] = s;
        sstat[1][tid] = betaL[tid] - mu * s;
    }
    WAITV0();
    __syncthreads();                        // slab landed + coeffs visible

    const int r  = tid >> 3;                // 0..63: row
    const int q8 = tid & 7;                 // 0..7: 24-channel group
    // ---- phase 2: apply relu(bn(.)) in place on the own-row slab
    {
        ushort* rowp = smem + r * RS + q8 * 24;
        #pragma unroll
        for (int k = 0; k < 3; ++k) {
            uint4 hv = *(uint4*)(rowp + k * 8);
            uint hu[4] = {hv.x, hv.y, hv.z, hv.w};
            ushort oh[8];
            #pragma unroll
            for (int e = 0; e < 4; ++e) {
                int ch = q8 * 24 + k * 8 + e * 2;
                float v0 = h2f((ushort)(hu[e] & 0xffffu)) * sstat[0][ch]     + sstat[1][ch];
                float v1 = h2f((ushort)(hu[e] >> 16))     * sstat[0][ch + 1] + sstat[1][ch + 1];
                oh[2*e]   = f2h(fmaxf(v0, 0.f));
                oh[2*e+1] = f2h(fmaxf(v1, 0.f));
            }
            *(uint4*)(rowp + k * 8) = pack8(oh);
        }
    }
    __syncthreads();                        // A2 (BN'd own rows) ready

    // ---- K-loop setup: wave = rg(2) x cg(4); wave tile 32 rows x 48 cols
    const int rg = wave >> 2;
    const int cg = wave & 3;

    auto loadB = [&](const ushort* Wf, int kc, half8* b) {
        const ushort* Bp = Wf + (size_t)kc * 6144
                         + (size_t)(cg * 192 + lane) * 8;
        #pragma unroll
        for (int ct = 0; ct < 3; ++ct)
            b[ct] = *(const half8*)(Bp + ct * 512);
    };

    floatx4 acc[2][3];
    #pragma unroll
    for (int s = 0; s < 2; ++s)
        #pragma unroll
        for (int ct = 0; ct < 3; ++ct) acc[s][ct] = (floatx4){0.f, 0.f, 0.f, 0.f};

    auto gemmPass = [&](const ushort* Wf) {
        half8 bA[3], bB[3];
        loadB(Wf, 0, bA);
        #pragma unroll
        for (int kc = 0; kc < NKC; ++kc) {
            if (kc + 1 < NKC) loadB(Wf, kc + 1, (kc & 1) ? bA : bB);
            const ushort* aB = smem + (rg * 32 + m16) * RS + kc * 32 + g4 * 8;
            half8 a[2];
            #pragma unroll
            for (int s = 0; s < 2; ++s)
                a[s] = *(const half8*)(aB + s * 16 * RS);
            const half8* bu = (kc & 1) ? bB : bA;
            #pragma unroll
            for (int ct = 0; ct < 3; ++ct)
                #pragma unroll
                for (int s = 0; s < 2; ++s)
                    acc[s][ct] = __builtin_amdgcn_mfma_f32_16x16x32_f16(a[s], bu[ct], acc[s][ct], 0, 0, 0);
        }
    };

    // ---- PASS 1: own rows x Wroot
    gemmPass(W2f);
    __syncthreads();                        // all waves done reading A2 slab

    // ---- phase 3: gather neighbors -> OVERWRITE slab with A1 (8 thr/row)
    {
        float acg[24];
        #pragma unroll
        for (int i = 0; i < 24; ++i) acg[i] = 0.f;
        int rr = row0 + r;
        if (rr < N) {
            int j0 = row_ptr[rr], j1 = row_ptr[rr + 1];
            const ushort* hp = Hraw + q8 * 24;
            for (int j = j0; j < j1; ++j) {
                int s = col[j];
                const ushort* rp = hp + (size_t)s * KR;
                uint4 h0 = *(const uint4*)(rp);
                uint4 h1 = *(const uint4*)(rp + 8);
                uint4 h2 = *(const uint4*)(rp + 16);
                uint hu[12] = {h0.x,h0.y,h0.z,h0.w, h1.x,h1.y,h1.z,h1.w,
                               h2.x,h2.y,h2.z,h2.w};
                #pragma unroll
                for (int e = 0; e < 12; ++e) {
                    int ch = q8 * 24 + e * 2;
                    float v0 = h2f((ushort)(hu[e] & 0xffffu)) * sstat[0][ch]     + sstat[1][ch];
                    float v1 = h2f((ushort)(hu[e] >> 16))     * sstat[0][ch + 1] + sstat[1][ch + 1];
                    acg[e*2]     += fmaxf(v0, 0.f);
                    acg[e*2 + 1] += fmaxf(v1, 0.f);
                }
            }
        }
        ushort* dst = smem + r * RS + q8 * 24;
        #pragma unroll
        for (int ck = 0; ck < 3; ++ck) {
            ushort oh[8];
            #pragma unroll
            for (int e = 0; e < 8; ++e) oh[e] = f2h(acg[ck*8 + e]);
            *(uint4*)(dst + ck * 8) = pack8(oh);
        }
    }
    __syncthreads();                        // A1 slab ready; coeffs consumed
    if (tid < HDIM) { sstat[0][tid] = 0.f; sstat[1][tid] = 0.f; }
    // (post-pass-2 __syncthreads orders this zero vs the stat atomics)

    // ---- PASS 2: gathered rows x Wrel
    gemmPass(W1f);

    // ---- epilogue (deg*bias, stats, C-tile, burst)
    __syncthreads();                        // pass-2 reads done; zero visible
    #pragma unroll
    for (int ct = 0; ct < 3; ++ct) {
        int colc = cg * 48 + ct * 16 + m16;
        float bv = bias[colc];
        float lsum = 0.f, lsq = 0.f;
        #pragma unroll
        for (int s = 0; s < 2; ++s) {
            #pragma unroll
            for (int reg = 0; reg < 4; ++reg) {
                int rloc = rg * 32 + s * 16 + g4 * 4 + reg;
                int rr = row0 + rloc;
                int rrc = rr < N ? rr : N - 1;
                float v = acc[s][ct][reg] + degf[rrc] * bv;
                if (rr < N) { lsum += v; lsq += v * v; }
                smem[rloc * 200 + colc] = f2h(v);
            }
        }
        lsum += __shfl_xor(lsum, 16); lsum += __shfl_xor(lsum, 32);
        lsq  += __shfl_xor(lsq, 16);  lsq  += __shfl_xor(lsq, 32);
        if (g4 == 0) {
            atomicAdd(&sstat[0][colc], lsum);   // rg=0,1 waves both add
            atomicAdd(&sstat[1][colc], lsq);
        }
    }
    __syncthreads();
    {
        int rowsLeft = N - row0; if (rowsLeft > 64) rowsLeft = 64;
        int lim = rowsLeft * 24;
        ushort* Cb = C + (size_t)row0 * HDIM;
        #pragma unroll
        for (int k = 0; k < 3; ++k) {
            int u = tid + k * 512;
            if (u < lim) {
                int rr = u / 24;
                int c8 = (u - rr * 24) * 8;
                *(uint4*)(Cb + (size_t)u * 8) =
                    *(const uint4*)(smem + rr * 200 + c8);
            }
        }
    }
    if (tid < HDIM) {
        float* pb = pstats + (size_t)blockIdx.x * (2 * HDIM);
        pb[tid]        = sstat[0][tid];
        pb[HDIM + tid] = sstat[1][tid];
    }
}

// ---------------------------------------------------------------------------
// sum per-block BN partials: pbuf[nb][384] -> stats[384].
// ---------------------------------------------------------------------------
__global__ __launch_bounds__(256) void bn_reduce_k(
    const float* __restrict__ pbuf, float* __restrict__ stats, int nb)
{
    __shared__ float red[32][9];           // +1 pad
    int t  = threadIdx.x;
    int cl = t & 7;
    int s  = t >> 3;
    int c  = blockIdx.x * 8 + cl;
    float acc = 0.f;
    int b = s;
    for (; b + 96 < nb; b += 128) {
        float a0 = pbuf[(size_t)b * 384 + c];
        float a1 = pbuf[(size_t)(b + 32) * 384 + c];
        float a2 = pbuf[(size_t)(b + 64) * 384 + c];
        float a3 = pbuf[(size_t)(b + 96) * 384 + c];
        acc += a0 + a1 + a2 + a3;
    }
    for (; b < nb; b += 32)
        acc += pbuf[(size_t)b * 384 + c];
    red[s][cl] = acc;
    __syncthreads();
    if (t < 8) {
        float a = 0.f;
        #pragma unroll
        for (int i = 0; i < 32; ++i) a += red[i][t];
        stats[blockIdx.x * 8 + t] = a;
    }
}

// ---------------------------------------------------------------------------
// CSR construction from edge_dst
// ---------------------------------------------------------------------------
__global__ __launch_bounds__(256) void hist_k(
    const int* __restrict__ dst, int* __restrict__ deg, int E)
{
    int e = blockIdx.x * 256 + threadIdx.x;
    if (e < E) atomicAdd(&deg[dst[e]], 1);
}

__global__ __launch_bounds__(256) void block_sum_k(
    const int* __restrict__ deg, int* __restrict__ bsum, int N)
{
    __shared__ int s[256];
    int t = threadIdx.x;
    int n = blockIdx.x * 256 + t;
    s[t] = (n < N) ? deg[n] : 0;
    __syncthreads();
    for (int off = 128; off > 0; off >>= 1) {
        if (t < off) s[t] += s[t + off];
        __syncthreads();
    }
    if (t == 0) bsum[blockIdx.x] = s[0];
}

__global__ __launch_bounds__(512) void scan_bsum_k(int* __restrict__ bsum, int nb)
{
    __shared__ int s[512];
    int t = threadIdx.x;
    int v = (t < nb) ? bsum[t] : 0;
    s[t] = v;
    __syncthreads();
    for (int off = 1; off < 512; off <<= 1) {
        int u = (t >= off) ? s[t - off] : 0;
        __syncthreads();
        s[t] += u;
        __syncthreads();
    }
    if (t < nb) bsum[t] = s[t] - v;   // exclusive
}

__global__ __launch_bounds__(256) void row_ptr_k(
    const int* __restrict__ deg, const int* __restrict__ bsum,
    int* __restrict__ row_ptr, int* __restrict__ cursor,
    float* __restrict__ degf, int N, int E)
{
    __shared__ int s[256];
    int t = threadIdx.x;
    int n = blockIdx.x * 256 + t;
    int v = (n < N) ? deg[n] : 0;
    s[t] = v;
    __syncthreads();
    for (int off = 1; off < 256; off <<= 1) {
        int u = (t >= off) ? s[t - off] : 0;
        __syncthreads();
        s[t] += u;
        __syncthreads();
    }
    int ex = s[t] - v + bsum[blockIdx.x];
    if (n < N) {
        row_ptr[n] = ex;
        cursor[n]  = ex;
        degf[n]    = (float)v;
    }
    if (blockIdx.x == 0 && t == 0) row_ptr[N] = E;
}

__global__ __launch_bounds__(256) void fill_k(
    const int* __restrict__ src, const int* __restrict__ dst,
    int* __restrict__ cursor, int* __restrict__ col, int E)
{
    int e = blockIdx.x * 256 + threadIdx.x;
    if (e < E) {
        int p = atomicAdd(&cursor[dst[e]], 1);
        col[p] = src[e];
    }
}

// ---------------------------------------------------------------------------
// plain gather (layer 0, no BN): g[n] = sum_j x[col[j]]; row-major fp16.
// ---------------------------------------------------------------------------
__global__ __launch_bounds__(256) void gather_h_k(
    const ushort* __restrict__ xh, const int* __restrict__ row_ptr,
    const int* __restrict__ col, ushort* __restrict__ gh, int N, int K)
{
    int OC = K >> 3;
    int idx = blockIdx.x * 256 + threadIdx.x;
    if (idx >= N * OC) return;
    int n = idx / OC;
    int o = idx - n * OC;
    const ushort* hp = xh + o * 8;
    int j0 = row_ptr[n], j1 = row_ptr[n + 1];
    float acc[8] = {0.f,0.f,0.f,0.f,0.f,0.f,0.f,0.f};
    auto addrow = [&](uint4 hv) {
        uint hu[4] = {hv.x, hv.y, hv.z, hv.w};
        #pragma unroll
        for (int t = 0; t < 4; ++t) {
            acc[2*t]   += h2f((ushort)(hu[t] & 0xffffu));
            acc[2*t+1] += h2f((ushort)(hu[t] >> 16));
        }
    };
    int j = j0;
    for (; j + 3 < j1; j += 4) {
        int s0 = col[j], s1 = col[j+1], s2 = col[j+2], s3 = col[j+3];
        uint4 v0 = *(const uint4*)(hp + (size_t)s0 * K);
        uint4 v1 = *(const uint4*)(hp + (size_t)s1 * K);
        uint4 v2 = *(const uint4*)(hp + (size_t)s2 * K);
        uint4 v3 = *(const uint4*)(hp + (size_t)s3 * K);
        addrow(v0); addrow(v1); addrow(v2); addrow(v3);
    }
    for (; j < j1; ++j)
        addrow(*(const uint4*)(hp + (size_t)col[j] * K));
    ushort oh[8];
    #pragma unroll
    for (int t = 0; t < 8; ++t) oh[t] = f2h(acc[t]);
    *(uint4*)(gh + (size_t)n * K + o * 8) = pack8(oh);
}

// ---------------------------------------------------------------------------
// fused final-BN + mean-pool
// ---------------------------------------------------------------------------
__global__ __launch_bounds__(192) void pool_bn_k(
    const ushort* __restrict__ h, const float* __restrict__ stats,
    const float* __restrict__ gamma, const float* __restrict__ beta,
    float invN, const int* __restrict__ batch,
    ushort* __restrict__ gsh, int G, int N)
{
    __shared__ int bounds[2];
    int g = blockIdx.x;
    int c = threadIdx.x;
    if (c < 2) {
        int key = g + c;
        int lo = 0, hi = N;
        while (lo < hi) {
            int mid = (lo + hi) >> 1;
            if (batch[mid] < key) lo = mid + 1; else hi = mid;
        }
        bounds[c] = lo;
    }
    __syncthreads();
    int r0 = bounds[0], r1 = bounds[1];
    float mu  = stats[c] * invN;
    float var = stats[HDIM + c] * invN - mu * mu;
    float sc  = gamma[c] * rsqrtf(var + EPS);
    float sh  = beta[c] - mu * sc;
    const ushort* base = h + c;
    float s = 0.f;
    for (int r = r0; r < r1; ++r)
        s += fmaxf(h2f(base[(size_t)r * HDIM]) * sc + sh, 0.f);
    float m = s / fmaxf((float)(r1 - r0), 1.f);
    gsh[(size_t)g * HDIM + c] = f2h(m);
}

// ---------------------------------------------------------------------------
// out[g] = dot(g2[g,:], Wout) + bout ; g2 is fp16 row-major
// ---------------------------------------------------------------------------
__global__ __launch_bounds__(64) void out_dot_k(
    const ushort* __restrict__ g2h, const float* __restrict__ Wout,
    const float* __restrict__ bout, float* __restrict__ out, int G)
{
    int gi = blockIdx.x;
    int t = threadIdx.x;
    float s = 0.f;
    #pragma unroll
    for (int j = 0; j < 3; ++j) {
        int c = t + j * 64;
        s += h2f(g2h[(size_t)gi * HDIM + c]) * Wout[c];
    }
    #pragma unroll
    for (int off = 32; off > 0; off >>= 1) s += __shfl_down(s, off, 64);
    if (t == 0) out[gi] = s + bout[0];
}

// ---------------------------------------------------------------------------
extern "C" void kernel_launch(void* const* d_in, const int* in_sizes, int n_in,
                              void* d_out, int out_size, void* d_ws, size_t ws_size,
                              hipStream_t stream)
{
    const float* x      = (const float*)d_in[0];
    const int*   esrc   = (const int*)d_in[1];
    const int*   edst   = (const int*)d_in[2];
    const int*   batch  = (const int*)d_in[3];
    const float* Wrel0  = (const float*)d_in[4];
    const float* brel0  = (const float*)d_in[5];
    const float* Wroot0 = (const float*)d_in[6];
    const float* Wrel   = (const float*)d_in[7];
    const float* brel   = (const float*)d_in[8];
    const float* Wroot  = (const float*)d_in[9];
    const float* gamma  = (const float*)d_in[10];
    const float* beta   = (const float*)d_in[11];
    const float* Wh1    = (const float*)d_in[12];
    const float* bh1    = (const float*)d_in[13];
    const float* Wh2    = (const float*)d_in[14];
    const float* bh2    = (const float*)d_in[15];
    const float* Wout   = (const float*)d_in[16];
    const float* bout   = (const float*)d_in[17];
    float* out = (float*)d_out;

    const int N  = in_sizes[3];           // 100000
    const int E  = in_sizes[1];           // 400000
    const int K0 = in_sizes[0] / N;       // 32
    const int G  = out_size;              // 2000
    const int nBlocks = (N + 255) / 256;
    const float invN = 1.0f / (float)N;

    char* p = (char*)d_ws;
    auto carve = [&](size_t bytes) -> void* {
        void* r = (void*)p; p += (bytes + 255) & ~(size_t)255; return r;
    };
    ushort* bufa_h= (ushort*)carve((size_t)N * HDIM * 2);   // raw conv h (ping)
    ushort* bufb_h= (ushort*)carve((size_t)N * HDIM * 2);   // raw conv h (pong)
    ushort* xh    = (ushort*)carve((size_t)N * K0 * 2);     // layer0 input fp16
    ushort* gh    = (ushort*)carve((size_t)N * K0 * 2);     // layer0 gathered
    ushort* gsh   = (ushort*)carve((size_t)G * HDIM * 2);
    ushort* g1h   = (ushort*)carve((size_t)G * HDIM * 2);
    ushort* g2h   = (ushort*)carve((size_t)G * HDIM * 2);
    // deg + bnsums adjacent -> single memset
    int*    deg   = (int*)   carve((size_t)N * 4);
    float*  bnsums= (float*) carve(4 * 2 * HDIM * 4);
    size_t  zspan = (char*)(bnsums + 4 * 2 * HDIM) - (char*)deg;
    float*  degf  = (float*) carve((size_t)N * 4);
    int*    row_ptr=(int*)   carve((size_t)(N + 1) * 4);
    int*    cursor= (int*)   carve((size_t)N * 4);
    int*    col   = (int*)   carve((size_t)E * 4);
    int*    bsum  = (int*)   carve((size_t)nBlocks * 4);
    ushort* Wrel0f= (ushort*)carve((size_t)K0 * HDIM * 2);
    ushort* Wroot0f=(ushort*)carve((size_t)K0 * HDIM * 2);
    ushort* Wrelf = (ushort*)carve((size_t)3 * HDIM * HDIM * 2);
    ushort* Wrootf= (ushort*)carve((size_t)3 * HDIM * HDIM * 2);
    ushort* Wh1f  = (ushort*)carve((size_t)HDIM * HDIM * 2);
    ushort* Wh2f  = (ushort*)carve((size_t)HDIM * HDIM * 2);

    dim3 b256(256);
    const int eBlocks = (E + 255) / 256;
    const int gemmN = (N + 63) / 64;
    const int gemmG = (G + 63) / 64;

    float*  pbuf  = (float*) carve((size_t)gemmN * 2 * HDIM * 4);  // BN partials

    // ---- merged weight prep (1 launch)
    {
        PrepArgs a;
        int t0 = (K0 >> 5) * 12 * 64;        // 768
        int t1 = (HDIM >> 5) * 12 * 64;      // 4608
        a.src[0] = Wrel0;  a.dst[0] = Wrel0f;  a.K[0] = K0;
        a.src[1] = Wroot0; a.dst[1] = Wroot0f; a.K[1] = K0;
        a.src[2] = Wrel;   a.dst[2] = Wrelf;   a.K[2] = HDIM;
        a.src[3] = Wroot;  a.dst[3] = Wrootf;  a.K[3] = HDIM;
        a.src[4] = Wh1;    a.dst[4] = Wh1f;    a.K[4] = HDIM;
        a.src[5] = Wh2;    a.dst[5] = Wh2f;    a.K[5] = HDIM;
        a.off[0] = 0;
        a.off[1] = a.off[0] + t0;
        a.off[2] = a.off[1] + t0;
        a.off[3] = a.off[2] + 3 * t1;
        a.off[4] = a.off[3] + 3 * t1;
        a.off[5] = a.off[4] + t1;
        a.off[6] = a.off[5] + t1;
        prep_all_k<<<(a.off[6] + 255) / 256, b256, 0, stream>>>(a);
    }
    // x -> row-major fp16 [N][32]
    conv_half_k<<<((N * (K0 >> 3)) + 255) / 256, b256, 0, stream>>>(x, xh, N, K0);

    // ---- CSR build
    hipMemsetAsync(deg, 0, zspan, stream);   // zeros deg + bnsums
    hist_k<<<eBlocks, b256, 0, stream>>>(edst, deg, E);
    block_sum_k<<<nBlocks, b256, 0, stream>>>(deg, bsum, N);
    scan_bsum_k<<<1, dim3(512), 0, stream>>>(bsum, nBlocks);
    row_ptr_k<<<nBlocks, b256, 0, stream>>>(deg, bsum, row_ptr, cursor, degf, N, E);
    fill_k<<<eBlocks, b256, 0, stream>>>(esrc, edst, cursor, col, E);

    // ---- layer 0 (input x, no input BN): K=32 dual -> NKC=1; writes bufa
    gather_h_k<<<((N * (K0 >> 3)) + 255) / 256, b256, 0, stream>>>(
        xh, row_ptr, col, gh, N, K0);
    gemm_mfma_k<true, false, true, true, 1><<<gemmN, b256, 0, stream>>>(
        gh, Wrel0f, xh, Wroot0f, degf, brel0, bufa_h, pbuf, N, K0);
    bn_reduce_k<<<48, b256, 0, stream>>>(pbuf, bnsums, gemmN);

    // ---- layers 1..3: FUSED single-slab two-pass, ping-pong bufa<->bufb
    ushort* rd = bufa_h;
    ushort* wr = bufb_h;
    for (int l = 1; l < 4; ++l) {
        const ushort* Wrf = Wrelf  + (size_t)(l - 1) * HDIM * HDIM;
        const ushort* Wtf = Wrootf + (size_t)(l - 1) * HDIM * HDIM;
        const float*  br  = brel   + (size_t)(l - 1) * HDIM;
        const float*  st  = bnsums + (size_t)(l - 1) * 2 * HDIM;
        const float*  gm  = gamma  + (size_t)(l - 1) * HDIM;
        const float*  bt  = beta   + (size_t)(l - 1) * HDIM;
        gemm_fused_k<<<gemmN, dim3(512), 0, stream>>>(
            rd, Wrf, Wtf, degf, br, st, gm, bt, invN,
            row_ptr, col, wr, pbuf, N);
        bn_reduce_k<<<48, b256, 0, stream>>>(pbuf, bnsums + l * 2 * HDIM, gemmN);
        ushort* tmp = rd; rd = wr; wr = tmp;
    }
    // after 3 layers: rd holds the final raw h (bufb)

    // ---- fused final BN + mean pool -> fp16 row-major head input
    pool_bn_k<<<G, dim3(192), 0, stream>>>(
        rd, bnsums + 3 * 2 * HDIM, gamma + 3 * HDIM, beta + 3 * HDIM,
        invN, batch, gsh, G, N);

    // ---- head MLP (MFMA path, row-major fp16 end-to-end; K=192 -> NKC=6)
    gemm_mfma_k<false, true, false, false, 6><<<gemmG, b256, 0, stream>>>(
        gsh, Wh1f, nullptr, nullptr, nullptr, bh1, g1h, nullptr, G, HDIM);
    gemm_mfma_k<false, false, false, false, 6><<<gemmG, b256, 0, stream>>>(
        g1h, Wh2f, nullptr, nullptr, nullptr, bh2, g2h, nullptr, G, HDIM);
    out_dot_k<<<G, dim3(64), 0, stream>>>(g2h, Wout, bout, out, G);
}

// Round 12
// 613.477 us; speedup vs baseline: 1.3766x; 1.3766x over previous
//
#include <hip/hip_runtime.h>

#define HDIM 192
#define EPS 1e-5f

typedef __attribute__((ext_vector_type(8))) _Float16 half8;
typedef __attribute__((ext_vector_type(4))) float floatx4;

__device__ __forceinline__ float h2f(ushort u) {
    union { ushort u; _Float16 h; } c; c.u = u; return (float)c.h;
}
__device__ __forceinline__ ushort f2h(float x) {
    _Float16 h = (_Float16)x;           // RTN
    union { _Float16 h; ushort u; } c; c.h = h; return c.u;
}
__device__ __forceinline__ uint4 pack8(const ushort* h) {
    uint4 p;
    p.x = h[0] | ((uint)h[1] << 16); p.y = h[2] | ((uint)h[3] << 16);
    p.z = h[4] | ((uint)h[5] << 16); p.w = h[6] | ((uint)h[7] << 16);
    return p;
}

// async global->LDS DMA, 16B per lane; LDS dest = wave-uniform base + lane*16,
// global source is PER-LANE (guide m104/m173).
__device__ __forceinline__ void gload_lds16(const ushort* g, ushort* l) {
    __builtin_amdgcn_global_load_lds(
        (const __attribute__((address_space(1))) unsigned int*)g,
        (__attribute__((address_space(3))) unsigned int*)l, 16, 0, 0);
}

#define WAITV0() asm volatile("s_waitcnt vmcnt(0)" ::: "memory")

// Activations are ROW-MAJOR fp16 [R][K].

// ---------------------------------------------------------------------------
// Merged weight prep: all 10 matrices in ONE launch.
// ---------------------------------------------------------------------------
struct PrepArgs {
    const float* src[6];
    ushort*      dst[6];
    int K[6];
    int off[7];       // thread offsets (per entry: nmat*(K/32)*12*64)
};

__global__ __launch_bounds__(256) void prep_all_k(PrepArgs a)
{
    int idx = blockIdx.x * 256 + threadIdx.x;
    if (idx >= a.off[6]) return;
    int i = 0;
    #pragma unroll
    for (int t = 1; t < 6; ++t) if (idx >= a.off[t]) i = t;
    int r = idx - a.off[i];
    int K = a.K[i];
    int perMat = (K >> 5) * 12 * 64;
    int mat = r / perMat;
    r -= mat * perMat;
    int lane = r & 63;
    int ct = (r >> 6) % 12;
    int kc = r / (12 * 64);
    int col = ct * 16 + (lane & 15);
    int kb  = kc * 32 + (lane >> 4) * 8;
    const float* Wm = a.src[i] + (size_t)mat * K * HDIM;
    ushort* base = a.dst[i] + (size_t)mat * K * HDIM;
    size_t o = (size_t)kc * 6144 + (size_t)(ct * 64 + lane) * 8;
    #pragma unroll
    for (int j = 0; j < 8; ++j)
        base[o + j] = f2h(Wm[(size_t)(kb + j) * HDIM + col]);
}

// ---------------------------------------------------------------------------
// fp32 row-major [R, C] -> fp16 row-major. One thread per 8 channels.
// ---------------------------------------------------------------------------
__global__ __launch_bounds__(256) void conv_half_k(
    const float* __restrict__ src, ushort* __restrict__ dst, int R, int C)
{
    int OC = C >> 3;
    int idx = blockIdx.x * 256 + threadIdx.x;
    if (idx >= R * OC) return;
    int r = idx / OC;
    int o = idx - r * OC;
    float4 v0 = ((const float4*)(src + (size_t)r * C + o * 8))[0];
    float4 v1 = ((const float4*)(src + (size_t)r * C + o * 8))[1];
    float v[8] = {v0.x, v0.y, v0.z, v0.w, v1.x, v1.y, v1.z, v1.w};
    ushort h[8];
    #pragma unroll
    for (int t = 0; t < 8; ++t) h[t] = f2h(v[t]);
    *(uint4*)(dst + (size_t)r * C + o * 8) = pack8(h);
}

// ---------------------------------------------------------------------------
// MFMA GEMM (layer0 + head): slab staging, barrier-free K-loop, LDS C-tile,
// per-block BN partials (no global atomics).  256 thr / 4 waves.
// ---------------------------------------------------------------------------
template<bool DUAL, bool RELU, bool DEG, bool STATS, int NKC>
__global__ __launch_bounds__(256, 3) void gemm_mfma_k(
    const ushort* __restrict__ A1h, const ushort* __restrict__ W1f,
    const ushort* __restrict__ A2h, const ushort* __restrict__ W2f,
    const float* __restrict__ degf, const float* __restrict__ bias,
    ushort* __restrict__ C, float* __restrict__ pstats, int N, int K)
{
    constexpr int KR   = NKC * 32;          // A row length (ushorts)
    constexpr int RS   = KR + 8;            // padded LDS row stride (ushorts)
    constexpr int SLAB = 64 * RS;           // ushorts per slab
    constexpr int NINSTR = SLAB / 512;      // wave DMA instrs per slab (1KB each)
    constexpr int NCH  = DUAL ? 2 * NKC : NKC;
    constexpr int SMEMU = ((DUAL ? 2 * SLAB : SLAB) > 12800)
                            ? (DUAL ? 2 * SLAB : SLAB) : 12800;  // C-tile needs 64*200

    __shared__ float sstat[2][HDIM];
    __shared__ __align__(16) ushort smem[SMEMU];
    const int tid  = threadIdx.x;
    const int wave = tid >> 6;      // 0..3 = column group (48 cols each)
    const int lane = tid & 63;
    const int row0 = blockIdx.x * 64;
    const int m16 = lane & 15;
    const int g4  = lane >> 4;

    if (STATS && tid < HDIM) { sstat[0][tid] = 0.f; sstat[1][tid] = 0.f; }

    // ---- slab staging: linear LDS slots -> per-lane (row, offset) source
    auto stage = [&](const ushort* Ab, int slabOff) {
        #pragma unroll
        for (int i = wave; i < NINSTR; i += 4) {
            int slotB = i * 1024 + lane * 16;        // byte offset in slab
            int r   = slotB / (RS * 2);
            int off = slotB - r * (RS * 2);          // byte within padded row
            if (off >= KR * 2) off = KR * 2 - 16;    // pad slot: dup last 16B
            int rr = row0 + r; if (rr >= N) rr = N - 1;
            gload_lds16(Ab + (size_t)rr * KR + (off >> 1),
                        smem + slabOff + i * 512);   // wave-uniform dest base
        }
    };

    stage(A1h, 0);
    if constexpr (DUAL) stage(A2h, SLAB);
    WAITV0();
    __builtin_amdgcn_s_barrier();            // all waves' slab quarters landed
    __builtin_amdgcn_sched_barrier(0);

    auto loadB = [&](int c, half8* b) {
        bool ph = DUAL && (c >= NKC);
        int kc = ph ? c - NKC : c;
        const ushort* Bp = (ph ? W2f : W1f) + (size_t)kc * 6144
                         + (size_t)(wave * 192 + lane) * 8;
        #pragma unroll
        for (int ct = 0; ct < 3; ++ct)
            b[ct] = *(const half8*)(Bp + ct * 512);
    };

    floatx4 acc[4][3];
    #pragma unroll
    for (int s = 0; s < 4; ++s)
        #pragma unroll
        for (int ct = 0; ct < 3; ++ct) acc[s][ct] = (floatx4){0.f, 0.f, 0.f, 0.f};

    // ---- K-loop: pure LDS + MFMA, no barriers, B register-dbuf from L2
    half8 bA[3], bB[3];
    loadB(0, bA);
    #pragma unroll
    for (int c = 0; c < NCH; ++c) {
        if (c + 1 < NCH) loadB(c + 1, (c & 1) ? bA : bB);
        const int base = (DUAL && c >= NKC) ? SLAB : 0;
        const int kc   = (DUAL && c >= NKC) ? c - NKC : c;
        const ushort* aB = smem + base + m16 * RS + kc * 32 + g4 * 8;
        half8 a[4];
        #pragma unroll
        for (int s = 0; s < 4; ++s)
            a[s] = *(const half8*)(aB + s * 16 * RS);
        const half8* bu = (c & 1) ? bB : bA;
        #pragma unroll
        for (int ct = 0; ct < 3; ++ct)
            #pragma unroll
            for (int s = 0; s < 4; ++s)
                acc[s][ct] = __builtin_amdgcn_mfma_f32_16x16x32_f16(a[s], bu[ct], acc[s][ct], 0, 0, 0);
    }

    // ---- epilogue: acc -> LDS C-tile (reuses slab0) -> linear global burst
    __syncthreads();                // all waves done reading slabs
    // C/D layout col=lane&15, row=(lane>>4)*4+reg  [m89]
    #pragma unroll
    for (int ct = 0; ct < 3; ++ct) {
        int col = wave * 48 + ct * 16 + m16;
        float bv = bias ? bias[col] : 0.f;
        float lsum = 0.f, lsq = 0.f;
        #pragma unroll
        for (int s = 0; s < 4; ++s) {
            #pragma unroll
            for (int reg = 0; reg < 4; ++reg) {
                int rloc = s * 16 + g4 * 4 + reg;
                int rr = row0 + rloc;
                int rrc = rr < N ? rr : N - 1;
                float v = acc[s][ct][reg] + (DEG ? degf[rrc] * bv : bv);
                if (STATS && rr < N) { lsum += v; lsq += v * v; }
                if (RELU) v = fmaxf(v, 0.f);
                smem[rloc * 200 + col] = f2h(v);
            }
        }
        if (STATS) {
            lsum += __shfl_xor(lsum, 16); lsum += __shfl_xor(lsum, 32);
            lsq  += __shfl_xor(lsq, 16);  lsq  += __shfl_xor(lsq, 32);
            if (g4 == 0) {
                atomicAdd(&sstat[0][col], lsum);   // LDS atomics: cheap
                atomicAdd(&sstat[1][col], lsq);
            }
        }
    }
    __syncthreads();                // C-tile + sstat complete
    {
        int rowsLeft = N - row0; if (rowsLeft > 64) rowsLeft = 64;
        int lim = rowsLeft * 24;    // uint4 count (24 per row)
        ushort* Cb = C + (size_t)row0 * HDIM;
        #pragma unroll
        for (int k = 0; k < 6; ++k) {
            int u = tid + k * 256;
            if (u < lim) {
                int r  = u / 24;
                int c8 = (u - r * 24) * 8;
                *(uint4*)(Cb + (size_t)u * 8) =
                    *(const uint4*)(smem + r * 200 + c8);
            }
        }
    }
    if (STATS) {
        if (tid < HDIM) {
            float* pb = pstats + (size_t)blockIdx.x * (2 * HDIM);
            pb[tid]        = sstat[0][tid];
            pb[HDIM + tid] = sstat[1][tid];
        }
    }
}

// ---------------------------------------------------------------------------
// FUSED layer kernel (layers 1..3), 512 thr / 8 waves, SINGLE-SLAB two-pass.
// R11 ERRATUM: __launch_bounds__(512,8) capped VGPR at 64 < the ~84 this
// kernel needs (pass-1 MFMA acc live across the gather) -> massive scratch
// spill (VGPR 32, FETCH 450MB, WRITE 280MB, 209us).  Now (512,6): VGPR cap
// ~85, 6 waves/SIMD -> 3 blocks/CU x 8 waves = 24 waves/CU (75% ceiling),
// LDS 27.1KB not the limit.  Structure unchanged from R11:
//  stage own rows -> (BN coeffs under DMA) -> BN apply in LDS ->
//  PASS 1 acc += A2(own) x Wroot -> bar -> gather neighbors OVERWRITE slab
//  -> bar -> PASS 2 acc += A1 x Wrel -> epilogue.  Ping-pong C vs Hraw.
// ---------------------------------------------------------------------------
__global__ __launch_bounds__(512, 6) void gemm_fused_k(
    const ushort* __restrict__ Hraw, const ushort* __restrict__ W1f,
    const ushort* __restrict__ W2f,
    const float* __restrict__ degf, const float* __restrict__ bias,
    const float* __restrict__ instats, const float* __restrict__ gammaL,
    const float* __restrict__ betaL, float invN,
    const int* __restrict__ row_ptr, const int* __restrict__ col,
    ushort* __restrict__ C, float* __restrict__ pstats, int N)
{
    constexpr int KR   = 192;
    constexpr int RS   = 200;               // padded row stride (ushorts)
    constexpr int SLAB = 64 * RS;           // 12800 ushorts = 25.6KB
    constexpr int NINSTR = SLAB / 512;      // 25 DMA instrs per slab
    constexpr int NKC  = 6;

    __shared__ float sstat[2][HDIM];
    __shared__ __align__(16) ushort smem[SLAB];
    const int tid  = threadIdx.x;
    const int wave = tid >> 6;              // 0..7
    const int lane = tid & 63;
    const int row0 = blockIdx.x * 64;
    const int m16 = lane & 15;
    const int g4  = lane >> 4;

    // ---- phase 1: stage own raw rows into the slab
    #pragma unroll
    for (int i = wave; i < NINSTR; i += 8) {
        int slotB = i * 1024 + lane * 16;
        int r   = slotB / (RS * 2);
        int off = slotB - r * (RS * 2);
        if (off >= KR * 2) off = KR * 2 - 16;
        int rr = row0 + r; if (rr >= N) rr = N - 1;
        gload_lds16(Hraw + (size_t)rr * KR + (off >> 1),
                    smem + i * 512);
    }
    // BN coeffs computed while the DMA is in flight (only needs instats)
    if (tid < HDIM) {
        float mu  = instats[tid] * invN;
        float var = instats[HDIM + tid] * invN - mu * mu;
        float s = gammaL[tid] * rsqrtf(var + EPS);
        sstat[0][tid] = s;
        sstat[1][tid] = betaL[tid] - mu * s;
    }
    WAITV0();
    __syncthreads();                        // slab landed + coeffs visible

    const int r  = tid >> 3;                // 0..63: row
    const int q8 = tid & 7;                 // 0..7: 24-channel group
    // ---- phase 2: apply relu(bn(.)) in place on the own-row slab
    {
        ushort* rowp = smem + r * RS + q8 * 24;
        #pragma unroll
        for (int k = 0; k < 3; ++k) {
            uint4 hv = *(uint4*)(rowp + k * 8);
            uint hu[4] = {hv.x, hv.y, hv.z, hv.w};
            ushort oh[8];
            #pragma unroll
            for (int e = 0; e < 4; ++e) {
                int ch = q8 * 24 + k * 8 + e * 2;
                float v0 = h2f((ushort)(hu[e] & 0xffffu)) * sstat[0][ch]     + sstat[1][ch];
                float v1 = h2f((ushort)(hu[e] >> 16))     * sstat[0][ch + 1] + sstat[1][ch + 1];
                oh[2*e]   = f2h(fmaxf(v0, 0.f));
                oh[2*e+1] = f2h(fmaxf(v1, 0.f));
            }
            *(uint4*)(rowp + k * 8) = pack8(oh);
        }
    }
    __syncthreads();                        // A2 (BN'd own rows) ready

    // ---- K-loop setup: wave = rg(2) x cg(4); wave tile 32 rows x 48 cols
    const int rg = wave >> 2;
    const int cg = wave & 3;

    auto loadB = [&](const ushort* Wf, int kc, half8* b) {
        const ushort* Bp = Wf + (size_t)kc * 6144
                         + (size_t)(cg * 192 + lane) * 8;
        #pragma unroll
        for (int ct = 0; ct < 3; ++ct)
            b[ct] = *(const half8*)(Bp + ct * 512);
    };

    floatx4 acc[2][3];
    #pragma unroll
    for (int s = 0; s < 2; ++s)
        #pragma unroll
        for (int ct = 0; ct < 3; ++ct) acc[s][ct] = (floatx4){0.f, 0.f, 0.f, 0.f};

    auto gemmPass = [&](const ushort* Wf) {
        half8 bA[3], bB[3];
        loadB(Wf, 0, bA);
        #pragma unroll
        for (int kc = 0; kc < NKC; ++kc) {
            if (kc + 1 < NKC) loadB(Wf, kc + 1, (kc & 1) ? bA : bB);
            const ushort* aB = smem + (rg * 32 + m16) * RS + kc * 32 + g4 * 8;
            half8 a[2];
            #pragma unroll
            for (int s = 0; s < 2; ++s)
                a[s] = *(const half8*)(aB + s * 16 * RS);
            const half8* bu = (kc & 1) ? bB : bA;
            #pragma unroll
            for (int ct = 0; ct < 3; ++ct)
                #pragma unroll
                for (int s = 0; s < 2; ++s)
                    acc[s][ct] = __builtin_amdgcn_mfma_f32_16x16x32_f16(a[s], bu[ct], acc[s][ct], 0, 0, 0);
        }
    };

    // ---- PASS 1: own rows x Wroot
    gemmPass(W2f);
    __syncthreads();                        // all waves done reading A2 slab

    // ---- phase 3: gather neighbors -> OVERWRITE slab with A1 (8 thr/row)
    {
        float acg[24];
        #pragma unroll
        for (int i = 0; i < 24; ++i) acg[i] = 0.f;
        int rr = row0 + r;
        if (rr < N) {
            int j0 = row_ptr[rr], j1 = row_ptr[rr + 1];
            const ushort* hp = Hraw + q8 * 24;
            for (int j = j0; j < j1; ++j) {
                int s = col[j];
                const ushort* rp = hp + (size_t)s * KR;
                uint4 h0 = *(const uint4*)(rp);
                uint4 h1 = *(const uint4*)(rp + 8);
                uint4 h2 = *(const uint4*)(rp + 16);
                uint hu[12] = {h0.x,h0.y,h0.z,h0.w, h1.x,h1.y,h1.z,h1.w,
                               h2.x,h2.y,h2.z,h2.w};
                #pragma unroll
                for (int e = 0; e < 12; ++e) {
                    int ch = q8 * 24 + e * 2;
                    float v0 = h2f((ushort)(hu[e] & 0xffffu)) * sstat[0][ch]     + sstat[1][ch];
                    float v1 = h2f((ushort)(hu[e] >> 16))     * sstat[0][ch + 1] + sstat[1][ch + 1];
                    acg[e*2]     += fmaxf(v0, 0.f);
                    acg[e*2 + 1] += fmaxf(v1, 0.f);
                }
            }
        }
        ushort* dst = smem + r * RS + q8 * 24;
        #pragma unroll
        for (int ck = 0; ck < 3; ++ck) {
            ushort oh[8];
            #pragma unroll
            for (int e = 0; e < 8; ++e) oh[e] = f2h(acg[ck*8 + e]);
            *(uint4*)(dst + ck * 8) = pack8(oh);
        }
    }
    __syncthreads();                        // A1 slab ready; coeffs consumed
    if (tid < HDIM) { sstat[0][tid] = 0.f; sstat[1][tid] = 0.f; }
    // (post-pass-2 __syncthreads orders this zero vs the stat atomics)

    // ---- PASS 2: gathered rows x Wrel
    gemmPass(W1f);

    // ---- epilogue (deg*bias, stats, C-tile, burst)
    __syncthreads();                        // pass-2 reads done; zero visible
    #pragma unroll
    for (int ct = 0; ct < 3; ++ct) {
        int colc = cg * 48 + ct * 16 + m16;
        float bv = bias[colc];
        float lsum = 0.f, lsq = 0.f;
        #pragma unroll
        for (int s = 0; s < 2; ++s) {
            #pragma unroll
            for (int reg = 0; reg < 4; ++reg) {
                int rloc = rg * 32 + s * 16 + g4 * 4 + reg;
                int rr = row0 + rloc;
                int rrc = rr < N ? rr : N - 1;
                float v = acc[s][ct][reg] + degf[rrc] * bv;
                if (rr < N) { lsum += v; lsq += v * v; }
                smem[rloc * 200 + colc] = f2h(v);
            }
        }
        lsum += __shfl_xor(lsum, 16); lsum += __shfl_xor(lsum, 32);
        lsq  += __shfl_xor(lsq, 16);  lsq  += __shfl_xor(lsq, 32);
        if (g4 == 0) {
            atomicAdd(&sstat[0][colc], lsum);   // rg=0,1 waves both add
            atomicAdd(&sstat[1][colc], lsq);
        }
    }
    __syncthreads();
    {
        int rowsLeft = N - row0; if (rowsLeft > 64) rowsLeft = 64;
        int lim = rowsLeft * 24;
        ushort* Cb = C + (size_t)row0 * HDIM;
        #pragma unroll
        for (int k = 0; k < 3; ++k) {
            int u = tid + k * 512;
            if (u < lim) {
                int rr = u / 24;
                int c8 = (u - rr * 24) * 8;
                *(uint4*)(Cb + (size_t)u * 8) =
                    *(const uint4*)(smem + rr * 200 + c8);
            }
        }
    }
    if (tid < HDIM) {
        float* pb = pstats + (size_t)blockIdx.x * (2 * HDIM);
        pb[tid]        = sstat[0][tid];
        pb[HDIM + tid] = sstat[1][tid];
    }
}

// ---------------------------------------------------------------------------
// sum per-block BN partials: pbuf[nb][384] -> stats[384].
// ---------------------------------------------------------------------------
__global__ __launch_bounds__(256) void bn_reduce_k(
    const float* __restrict__ pbuf, float* __restrict__ stats, int nb)
{
    __shared__ float red[32][9];           // +1 pad
    int t  = threadIdx.x;
    int cl = t & 7;
    int s  = t >> 3;
    int c  = blockIdx.x * 8 + cl;
    float acc = 0.f;
    int b = s;
    for (; b + 96 < nb; b += 128) {
        float a0 = pbuf[(size_t)b * 384 + c];
        float a1 = pbuf[(size_t)(b + 32) * 384 + c];
        float a2 = pbuf[(size_t)(b + 64) * 384 + c];
        float a3 = pbuf[(size_t)(b + 96) * 384 + c];
        acc += a0 + a1 + a2 + a3;
    }
    for (; b < nb; b += 32)
        acc += pbuf[(size_t)b * 384 + c];
    red[s][cl] = acc;
    __syncthreads();
    if (t < 8) {
        float a = 0.f;
        #pragma unroll
        for (int i = 0; i < 32; ++i) a += red[i][t];
        stats[blockIdx.x * 8 + t] = a;
    }
}

// ---------------------------------------------------------------------------
// CSR construction from edge_dst
// ---------------------------------------------------------------------------
__global__ __launch_bounds__(256) void hist_k(
    const int* __restrict__ dst, int* __restrict__ deg, int E)
{
    int e = blockIdx.x * 256 + threadIdx.x;
    if (e < E) atomicAdd(&deg[dst[e]], 1);
}

__global__ __launch_bounds__(256) void block_sum_k(
    const int* __restrict__ deg, int* __restrict__ bsum, int N)
{
    __shared__ int s[256];
    int t = threadIdx.x;
    int n = blockIdx.x * 256 + t;
    s[t] = (n < N) ? deg[n] : 0;
    __syncthreads();
    for (int off = 128; off > 0; off >>= 1) {
        if (t < off) s[t] += s[t + off];
        __syncthreads();
    }
    if (t == 0) bsum[blockIdx.x] = s[0];
}

__global__ __launch_bounds__(512) void scan_bsum_k(int* __restrict__ bsum, int nb)
{
    __shared__ int s[512];
    int t = threadIdx.x;
    int v = (t < nb) ? bsum[t] : 0;
    s[t] = v;
    __syncthreads();
    for (int off = 1; off < 512; off <<= 1) {
        int u = (t >= off) ? s[t - off] : 0;
        __syncthreads();
        s[t] += u;
        __syncthreads();
    }
    if (t < nb) bsum[t] = s[t] - v;   // exclusive
}

__global__ __launch_bounds__(256) void row_ptr_k(
    const int* __restrict__ deg, const int* __restrict__ bsum,
    int* __restrict__ row_ptr, int* __restrict__ cursor,
    float* __restrict__ degf, int N, int E)
{
    __shared__ int s[256];
    int t = threadIdx.x;
    int n = blockIdx.x * 256 + t;
    int v = (n < N) ? deg[n] : 0;
    s[t] = v;
    __syncthreads();
    for (int off = 1; off < 256; off <<= 1) {
        int u = (t >= off) ? s[t - off] : 0;
        __syncthreads();
        s[t] += u;
        __syncthreads();
    }
    int ex = s[t] - v + bsum[blockIdx.x];
    if (n < N) {
        row_ptr[n] = ex;
        cursor[n]  = ex;
        degf[n]    = (float)v;
    }
    if (blockIdx.x == 0 && t == 0) row_ptr[N] = E;
}

__global__ __launch_bounds__(256) void fill_k(
    const int* __restrict__ src, const int* __restrict__ dst,
    int* __restrict__ cursor, int* __restrict__ col, int E)
{
    int e = blockIdx.x * 256 + threadIdx.x;
    if (e < E) {
        int p = atomicAdd(&cursor[dst[e]], 1);
        col[p] = src[e];
    }
}

// ---------------------------------------------------------------------------
// plain gather (layer 0, no BN): g[n] = sum_j x[col[j]]; row-major fp16.
// ---------------------------------------------------------------------------
__global__ __launch_bounds__(256) void gather_h_k(
    const ushort* __restrict__ xh, const int* __restrict__ row_ptr,
    const int* __restrict__ col, ushort* __restrict__ gh, int N, int K)
{
    int OC = K >> 3;
    int idx = blockIdx.x * 256 + threadIdx.x;
    if (idx >= N * OC) return;
    int n = idx / OC;
    int o = idx - n * OC;
    const ushort* hp = xh + o * 8;
    int j0 = row_ptr[n], j1 = row_ptr[n + 1];
    float acc[8] = {0.f,0.f,0.f,0.f,0.f,0.f,0.f,0.f};
    auto addrow = [&](uint4 hv) {
        uint hu[4] = {hv.x, hv.y, hv.z, hv.w};
        #pragma unroll
        for (int t = 0; t < 4; ++t) {
            acc[2*t]   += h2f((ushort)(hu[t] & 0xffffu));
            acc[2*t+1] += h2f((ushort)(hu[t] >> 16));
        }
    };
    int j = j0;
    for (; j + 3 < j1; j += 4) {
        int s0 = col[j], s1 = col[j+1], s2 = col[j+2], s3 = col[j+3];
        uint4 v0 = *(const uint4*)(hp + (size_t)s0 * K);
        uint4 v1 = *(const uint4*)(hp + (size_t)s1 * K);
        uint4 v2 = *(const uint4*)(hp + (size_t)s2 * K);
        uint4 v3 = *(const uint4*)(hp + (size_t)s3 * K);
        addrow(v0); addrow(v1); addrow(v2); addrow(v3);
    }
    for (; j < j1; ++j)
        addrow(*(const uint4*)(hp + (size_t)col[j] * K));
    ushort oh[8];
    #pragma unroll
    for (int t = 0; t < 8; ++t) oh[t] = f2h(acc[t]);
    *(uint4*)(gh + (size_t)n * K + o * 8) = pack8(oh);
}

// ---------------------------------------------------------------------------
// fused final-BN + mean-pool
// ---------------------------------------------------------------------------
__global__ __launch_bounds__(192) void pool_bn_k(
    const ushort* __restrict__ h, const float* __restrict__ stats,
    const float* __restrict__ gamma, const float* __restrict__ beta,
    float invN, const int* __restrict__ batch,
    ushort* __restrict__ gsh, int G, int N)
{
    __shared__ int bounds[2];
    int g = blockIdx.x;
    int c = threadIdx.x;
    if (c < 2) {
        int key = g + c;
        int lo = 0, hi = N;
        while (lo < hi) {
            int mid = (lo + hi) >> 1;
            if (batch[mid] < key) lo = mid + 1; else hi = mid;
        }
        bounds[c] = lo;
    }
    __syncthreads();
    int r0 = bounds[0], r1 = bounds[1];
    float mu  = stats[c] * invN;
    float var = stats[HDIM + c] * invN - mu * mu;
    float sc  = gamma[c] * rsqrtf(var + EPS);
    float sh  = beta[c] - mu * sc;
    const ushort* base = h + c;
    float s = 0.f;
    for (int r = r0; r < r1; ++r)
        s += fmaxf(h2f(base[(size_t)r * HDIM]) * sc + sh, 0.f);
    float m = s / fmaxf((float)(r1 - r0), 1.f);
    gsh[(size_t)g * HDIM + c] = f2h(m);
}

// ---------------------------------------------------------------------------
// out[g] = dot(g2[g,:], Wout) + bout ; g2 is fp16 row-major
// ---------------------------------------------------------------------------
__global__ __launch_bounds__(64) void out_dot_k(
    const ushort* __restrict__ g2h, const float* __restrict__ Wout,
    const float* __restrict__ bout, float* __restrict__ out, int G)
{
    int gi = blockIdx.x;
    int t = threadIdx.x;
    float s = 0.f;
    #pragma unroll
    for (int j = 0; j < 3; ++j) {
        int c = t + j * 64;
        s += h2f(g2h[(size_t)gi * HDIM + c]) * Wout[c];
    }
    #pragma unroll
    for (int off = 32; off > 0; off >>= 1) s += __shfl_down(s, off, 64);
    if (t == 0) out[gi] = s + bout[0];
}

// ---------------------------------------------------------------------------
extern "C" void kernel_launch(void* const* d_in, const int* in_sizes, int n_in,
                              void* d_out, int out_size, void* d_ws, size_t ws_size,
                              hipStream_t stream)
{
    const float* x      = (const float*)d_in[0];
    const int*   esrc   = (const int*)d_in[1];
    const int*   edst   = (const int*)d_in[2];
    const int*   batch  = (const int*)d_in[3];
    const float* Wrel0  = (const float*)d_in[4];
    const float* brel0  = (const float*)d_in[5];
    const float* Wroot0 = (const float*)d_in[6];
    const float* Wrel   = (const float*)d_in[7];
    const float* brel   = (const float*)d_in[8];
    const float* Wroot  = (const float*)d_in[9];
    const float* gamma  = (const float*)d_in[10];
    const float* beta   = (const float*)d_in[11];
    const float* Wh1    = (const float*)d_in[12];
    const float* bh1    = (const float*)d_in[13];
    const float* Wh2    = (const float*)d_in[14];
    const float* bh2    = (const float*)d_in[15];
    const float* Wout   = (const float*)d_in[16];
    const float* bout   = (const float*)d_in[17];
    float* out = (float*)d_out;

    const int N  = in_sizes[3];           // 100000
    const int E  = in_sizes[1];           // 400000
    const int K0 = in_sizes[0] / N;       // 32
    const int G  = out_size;              // 2000
    const int nBlocks = (N + 255) / 256;
    const float invN = 1.0f / (float)N;

    char* p = (char*)d_ws;
    auto carve = [&](size_t bytes) -> void* {
        void* r = (void*)p; p += (bytes + 255) & ~(size_t)255; return r;
    };
    ushort* bufa_h= (ushort*)carve((size_t)N * HDIM * 2);   // raw conv h (ping)
    ushort* bufb_h= (ushort*)carve((size_t)N * HDIM * 2);   // raw conv h (pong)
    ushort* xh    = (ushort*)carve((size_t)N * K0 * 2);     // layer0 input fp16
    ushort* gh    = (ushort*)carve((size_t)N * K0 * 2);     // layer0 gathered
    ushort* gsh   = (ushort*)carve((size_t)G * HDIM * 2);
    ushort* g1h   = (ushort*)carve((size_t)G * HDIM * 2);
    ushort* g2h   = (ushort*)carve((size_t)G * HDIM * 2);
    // deg + bnsums adjacent -> single memset
    int*    deg   = (int*)   carve((size_t)N * 4);
    float*  bnsums= (float*) carve(4 * 2 * HDIM * 4);
    size_t  zspan = (char*)(bnsums + 4 * 2 * HDIM) - (char*)deg;
    float*  degf  = (float*) carve((size_t)N * 4);
    int*    row_ptr=(int*)   carve((size_t)(N + 1) * 4);
    int*    cursor= (int*)   carve((size_t)N * 4);
    int*    col   = (int*)   carve((size_t)E * 4);
    int*    bsum  = (int*)   carve((size_t)nBlocks * 4);
    ushort* Wrel0f= (ushort*)carve((size_t)K0 * HDIM * 2);
    ushort* Wroot0f=(ushort*)carve((size_t)K0 * HDIM * 2);
    ushort* Wrelf = (ushort*)carve((size_t)3 * HDIM * HDIM * 2);
    ushort* Wrootf= (ushort*)carve((size_t)3 * HDIM * HDIM * 2);
    ushort* Wh1f  = (ushort*)carve((size_t)HDIM * HDIM * 2);
    ushort* Wh2f  = (ushort*)carve((size_t)HDIM * HDIM * 2);

    dim3 b256(256);
    const int eBlocks = (E + 255) / 256;
    const int gemmN = (N + 63) / 64;
    const int gemmG = (G + 63) / 64;

    float*  pbuf  = (float*) carve((size_t)gemmN * 2 * HDIM * 4);  // BN partials

    // ---- merged weight prep (1 launch)
    {
        PrepArgs a;
        int t0 = (K0 >> 5) * 12 * 64;        // 768
        int t1 = (HDIM >> 5) * 12 * 64;      // 4608
        a.src[0] = Wrel0;  a.dst[0] = Wrel0f;  a.K[0] = K0;
        a.src[1] = Wroot0; a.dst[1] = Wroot0f; a.K[1] = K0;
        a.src[2] = Wrel;   a.dst[2] = Wrelf;   a.K[2] = HDIM;
        a.src[3] = Wroot;  a.dst[3] = Wrootf;  a.K[3] = HDIM;
        a.src[4] = Wh1;    a.dst[4] = Wh1f;    a.K[4] = HDIM;
        a.src[5] = Wh2;    a.dst[5] = Wh2f;    a.K[5] = HDIM;
        a.off[0] = 0;
        a.off[1] = a.off[0] + t0;
        a.off[2] = a.off[1] + t0;
        a.off[3] = a.off[2] + 3 * t1;
        a.off[4] = a.off[3] + 3 * t1;
        a.off[5] = a.off[4] + t1;
        a.off[6] = a.off[5] + t1;
        prep_all_k<<<(a.off[6] + 255) / 256, b256, 0, stream>>>(a);
    }
    // x -> row-major fp16 [N][32]
    conv_half_k<<<((N * (K0 >> 3)) + 255) / 256, b256, 0, stream>>>(x, xh, N, K0);

    // ---- CSR build
    hipMemsetAsync(deg, 0, zspan, stream);   // zeros deg + bnsums
    hist_k<<<eBlocks, b256, 0, stream>>>(edst, deg, E);
    block_sum_k<<<nBlocks, b256, 0, stream>>>(deg, bsum, N);
    scan_bsum_k<<<1, dim3(512), 0, stream>>>(bsum, nBlocks);
    row_ptr_k<<<nBlocks, b256, 0, stream>>>(deg, bsum, row_ptr, cursor, degf, N, E);
    fill_k<<<eBlocks, b256, 0, stream>>>(esrc, edst, cursor, col, E);

    // ---- layer 0 (input x, no input BN): K=32 dual -> NKC=1; writes bufa
    gather_h_k<<<((N * (K0 >> 3)) + 255) / 256, b256, 0, stream>>>(
        xh, row_ptr, col, gh, N, K0);
    gemm_mfma_k<true, false, true, true, 1><<<gemmN, b256, 0, stream>>>(
        gh, Wrel0f, xh, Wroot0f, degf, brel0, bufa_h, pbuf, N, K0);
    bn_reduce_k<<<48, b256, 0, stream>>>(pbuf, bnsums, gemmN);

    // ---- layers 1..3: FUSED single-slab two-pass, ping-pong bufa<->bufb
    ushort* rd = bufa_h;
    ushort* wr = bufb_h;
    for (int l = 1; l < 4; ++l) {
        const ushort* Wrf = Wrelf  + (size_t)(l - 1) * HDIM * HDIM;
        const ushort* Wtf = Wrootf + (size_t)(l - 1) * HDIM * HDIM;
        const float*  br  = brel   + (size_t)(l - 1) * HDIM;
        const float*  st  = bnsums + (size_t)(l - 1) * 2 * HDIM;
        const float*  gm  = gamma  + (size_t)(l - 1) * HDIM;
        const float*  bt  = beta   + (size_t)(l - 1) * HDIM;
        gemm_fused_k<<<gemmN, dim3(512), 0, stream>>>(
            rd, Wrf, Wtf, degf, br, st, gm, bt, invN,
            row_ptr, col, wr, pbuf, N);
        bn_reduce_k<<<48, b256, 0, stream>>>(pbuf, bnsums + l * 2 * HDIM, gemmN);
        ushort* tmp = rd; rd = wr; wr = tmp;
    }
    // after 3 layers: rd holds the final raw h (bufb)

    // ---- fused final BN + mean pool -> fp16 row-major head input
    pool_bn_k<<<G, dim3(192), 0, stream>>>(
        rd, bnsums + 3 * 2 * HDIM, gamma + 3 * HDIM, beta + 3 * HDIM,
        invN, batch, gsh, G, N);

    // ---- head MLP (MFMA path, row-major fp16 end-to-end; K=192 -> NKC=6)
    gemm_mfma_k<false, true, false, false, 6><<<gemmG, b256, 0, stream>>>(
        gsh, Wh1f, nullptr, nullptr, nullptr, bh1, g1h, nullptr, G, HDIM);
    gemm_mfma_k<false, false, false, false, 6><<<gemmG, b256, 0, stream>>>(
        g1h, Wh2f, nullptr, nullptr, nullptr, bh2, g2h, nullptr, G, HDIM);
    out_dot_k<<<G, dim3(64), 0, stream>>>(g2h, Wout, bout, out, G);
}

// Round 13
// 530.711 us; speedup vs baseline: 1.5913x; 1.1560x over previous
//
#include <hip/hip_runtime.h>

#define HDIM 192
#define EPS 1e-5f

typedef __attribute__((ext_vector_type(8))) _Float16 half8;
typedef __attribute__((ext_vector_type(4))) float floatx4;

__device__ __forceinline__ float h2f(ushort u) {
    union { ushort u; _Float16 h; } c; c.u = u; return (float)c.h;
}
__device__ __forceinline__ ushort f2h(float x) {
    _Float16 h = (_Float16)x;           // RTN
    union { _Float16 h; ushort u; } c; c.h = h; return c.u;
}
__device__ __forceinline__ uint4 pack8(const ushort* h) {
    uint4 p;
    p.x = h[0] | ((uint)h[1] << 16); p.y = h[2] | ((uint)h[3] << 16);
    p.z = h[4] | ((uint)h[5] << 16); p.w = h[6] | ((uint)h[7] << 16);
    return p;
}

// async global->LDS DMA, 16B per lane; LDS dest = wave-uniform base + lane*16,
// global source is PER-LANE (guide m104/m173).
__device__ __forceinline__ void gload_lds16(const ushort* g, ushort* l) {
    __builtin_amdgcn_global_load_lds(
        (const __attribute__((address_space(1))) unsigned int*)g,
        (__attribute__((address_space(3))) unsigned int*)l, 16, 0, 0);
}

#define WAITV0() asm volatile("s_waitcnt vmcnt(0)" ::: "memory")

// Activations are ROW-MAJOR fp16 [R][K].

// ---------------------------------------------------------------------------
// Merged weight prep: all 10 matrices in ONE launch.
// ---------------------------------------------------------------------------
struct PrepArgs {
    const float* src[6];
    ushort*      dst[6];
    int K[6];
    int off[7];       // thread offsets (per entry: nmat*(K/32)*12*64)
};

__global__ __launch_bounds__(256) void prep_all_k(PrepArgs a)
{
    int idx = blockIdx.x * 256 + threadIdx.x;
    if (idx >= a.off[6]) return;
    int i = 0;
    #pragma unroll
    for (int t = 1; t < 6; ++t) if (idx >= a.off[t]) i = t;
    int r = idx - a.off[i];
    int K = a.K[i];
    int perMat = (K >> 5) * 12 * 64;
    int mat = r / perMat;
    r -= mat * perMat;
    int lane = r & 63;
    int ct = (r >> 6) % 12;
    int kc = r / (12 * 64);
    int col = ct * 16 + (lane & 15);
    int kb  = kc * 32 + (lane >> 4) * 8;
    const float* Wm = a.src[i] + (size_t)mat * K * HDIM;
    ushort* base = a.dst[i] + (size_t)mat * K * HDIM;
    size_t o = (size_t)kc * 6144 + (size_t)(ct * 64 + lane) * 8;
    #pragma unroll
    for (int j = 0; j < 8; ++j)
        base[o + j] = f2h(Wm[(size_t)(kb + j) * HDIM + col]);
}

// ---------------------------------------------------------------------------
// fp32 row-major [R, C] -> fp16 row-major. One thread per 8 channels.
// ---------------------------------------------------------------------------
__global__ __launch_bounds__(256) void conv_half_k(
    const float* __restrict__ src, ushort* __restrict__ dst, int R, int C)
{
    int OC = C >> 3;
    int idx = blockIdx.x * 256 + threadIdx.x;
    if (idx >= R * OC) return;
    int r = idx / OC;
    int o = idx - r * OC;
    float4 v0 = ((const float4*)(src + (size_t)r * C + o * 8))[0];
    float4 v1 = ((const float4*)(src + (size_t)r * C + o * 8))[1];
    float v[8] = {v0.x, v0.y, v0.z, v0.w, v1.x, v1.y, v1.z, v1.w};
    ushort h[8];
    #pragma unroll
    for (int t = 0; t < 8; ++t) h[t] = f2h(v[t]);
    *(uint4*)(dst + (size_t)r * C + o * 8) = pack8(h);
}

// ---------------------------------------------------------------------------
// MFMA GEMM (layer0 + head): slab staging, barrier-free K-loop, LDS C-tile,
// per-block BN partials (no global atomics).  256 thr / 4 waves.
// ---------------------------------------------------------------------------
template<bool DUAL, bool RELU, bool DEG, bool STATS, int NKC>
__global__ __launch_bounds__(256, 3) void gemm_mfma_k(
    const ushort* __restrict__ A1h, const ushort* __restrict__ W1f,
    const ushort* __restrict__ A2h, const ushort* __restrict__ W2f,
    const float* __restrict__ degf, const float* __restrict__ bias,
    ushort* __restrict__ C, float* __restrict__ pstats, int N, int K)
{
    constexpr int KR   = NKC * 32;          // A row length (ushorts)
    constexpr int RS   = KR + 8;            // padded LDS row stride (ushorts)
    constexpr int SLAB = 64 * RS;           // ushorts per slab
    constexpr int NINSTR = SLAB / 512;      // wave DMA instrs per slab (1KB each)
    constexpr int NCH  = DUAL ? 2 * NKC : NKC;
    constexpr int SMEMU = ((DUAL ? 2 * SLAB : SLAB) > 12800)
                            ? (DUAL ? 2 * SLAB : SLAB) : 12800;  // C-tile needs 64*200

    __shared__ float sstat[2][HDIM];
    __shared__ __align__(16) ushort smem[SMEMU];
    const int tid  = threadIdx.x;
    const int wave = tid >> 6;      // 0..3 = column group (48 cols each)
    const int lane = tid & 63;
    const int row0 = blockIdx.x * 64;
    const int m16 = lane & 15;
    const int g4  = lane >> 4;

    if (STATS && tid < HDIM) { sstat[0][tid] = 0.f; sstat[1][tid] = 0.f; }

    // ---- slab staging: linear LDS slots -> per-lane (row, offset) source
    auto stage = [&](const ushort* Ab, int slabOff) {
        #pragma unroll
        for (int i = wave; i < NINSTR; i += 4) {
            int slotB = i * 1024 + lane * 16;        // byte offset in slab
            int r   = slotB / (RS * 2);
            int off = slotB - r * (RS * 2);          // byte within padded row
            if (off >= KR * 2) off = KR * 2 - 16;    // pad slot: dup last 16B
            int rr = row0 + r; if (rr >= N) rr = N - 1;
            gload_lds16(Ab + (size_t)rr * KR + (off >> 1),
                        smem + slabOff + i * 512);   // wave-uniform dest base
        }
    };

    stage(A1h, 0);
    if constexpr (DUAL) stage(A2h, SLAB);
    WAITV0();
    __builtin_amdgcn_s_barrier();            // all waves' slab quarters landed
    __builtin_amdgcn_sched_barrier(0);

    auto loadB = [&](int c, half8* b) {
        bool ph = DUAL && (c >= NKC);
        int kc = ph ? c - NKC : c;
        const ushort* Bp = (ph ? W2f : W1f) + (size_t)kc * 6144
                         + (size_t)(wave * 192 + lane) * 8;
        #pragma unroll
        for (int ct = 0; ct < 3; ++ct)
            b[ct] = *(const half8*)(Bp + ct * 512);
    };

    floatx4 acc[4][3];
    #pragma unroll
    for (int s = 0; s < 4; ++s)
        #pragma unroll
        for (int ct = 0; ct < 3; ++ct) acc[s][ct] = (floatx4){0.f, 0.f, 0.f, 0.f};

    // ---- K-loop: pure LDS + MFMA, no barriers, B register-dbuf from L2
    half8 bA[3], bB[3];
    loadB(0, bA);
    #pragma unroll
    for (int c = 0; c < NCH; ++c) {
        if (c + 1 < NCH) loadB(c + 1, (c & 1) ? bA : bB);
        const int base = (DUAL && c >= NKC) ? SLAB : 0;
        const int kc   = (DUAL && c >= NKC) ? c - NKC : c;
        const ushort* aB = smem + base + m16 * RS + kc * 32 + g4 * 8;
        half8 a[4];
        #pragma unroll
        for (int s = 0; s < 4; ++s)
            a[s] = *(const half8*)(aB + s * 16 * RS);
        const half8* bu = (c & 1) ? bB : bA;
        #pragma unroll
        for (int ct = 0; ct < 3; ++ct)
            #pragma unroll
            for (int s = 0; s < 4; ++s)
                acc[s][ct] = __builtin_amdgcn_mfma_f32_16x16x32_f16(a[s], bu[ct], acc[s][ct], 0, 0, 0);
    }

    // ---- epilogue: acc -> LDS C-tile (reuses slab0) -> linear global burst
    __syncthreads();                // all waves done reading slabs
    // C/D layout col=lane&15, row=(lane>>4)*4+reg  [m89]
    #pragma unroll
    for (int ct = 0; ct < 3; ++ct) {
        int col = wave * 48 + ct * 16 + m16;
        float bv = bias ? bias[col] : 0.f;
        float lsum = 0.f, lsq = 0.f;
        #pragma unroll
        for (int s = 0; s < 4; ++s) {
            #pragma unroll
            for (int reg = 0; reg < 4; ++reg) {
                int rloc = s * 16 + g4 * 4 + reg;
                int rr = row0 + rloc;
                int rrc = rr < N ? rr : N - 1;
                float v = acc[s][ct][reg] + (DEG ? degf[rrc] * bv : bv);
                if (STATS && rr < N) { lsum += v; lsq += v * v; }
                if (RELU) v = fmaxf(v, 0.f);
                smem[rloc * 200 + col] = f2h(v);
            }
        }
        if (STATS) {
            lsum += __shfl_xor(lsum, 16); lsum += __shfl_xor(lsum, 32);
            lsq  += __shfl_xor(lsq, 16);  lsq  += __shfl_xor(lsq, 32);
            if (g4 == 0) {
                atomicAdd(&sstat[0][col], lsum);   // LDS atomics: cheap
                atomicAdd(&sstat[1][col], lsq);
            }
        }
    }
    __syncthreads();                // C-tile + sstat complete
    {
        int rowsLeft = N - row0; if (rowsLeft > 64) rowsLeft = 64;
        int lim = rowsLeft * 24;    // uint4 count (24 per row)
        ushort* Cb = C + (size_t)row0 * HDIM;
        #pragma unroll
        for (int k = 0; k < 6; ++k) {
            int u = tid + k * 256;
            if (u < lim) {
                int r  = u / 24;
                int c8 = (u - r * 24) * 8;
                *(uint4*)(Cb + (size_t)u * 8) =
                    *(const uint4*)(smem + r * 200 + c8);
            }
        }
    }
    if (STATS) {
        if (tid < HDIM) {
            float* pb = pstats + (size_t)blockIdx.x * (2 * HDIM);
            pb[tid]        = sstat[0][tid];
            pb[HDIM + tid] = sstat[1][tid];
        }
    }
}

// ---------------------------------------------------------------------------
// FUSED layer kernel (layers 1..3), 512 thr / 8 waves, DUAL-SLAB (R10
// structure: gather completes BEFORE the K-loop, so MFMA accumulators are
// never live across the irregular gather -- R11/R12's single-slab two-pass
// spilled catastrophically for exactly that reason).  NEW vs R10: the gather
// loop is unrolled x4 with hoisted col loads (4 independent edge chains in
// flight; R10's rolled loop was a ~700cy dependent chain per edge).
//  phase 1: stage own-row raw-h slab (A2) via global_load_lds.
//  phase 2: BN coeffs (under DMA); BN apply in LDS on A2; gather neighbors
//           (8 thr/row x 24 ch, unroll-4) -> A1 slab in LDS.
//  phase 3: barrier-free 12-chunk K-loop; 8 waves = 2 row-groups x 4
//           col-groups, wave tile 32x48, acc[2][3]; epilogue w/ BN partials.
// Output C MUST differ from Hraw (ping-pong).
// ---------------------------------------------------------------------------
__global__ __launch_bounds__(512, 4) void gemm_fused_k(
    const ushort* __restrict__ Hraw, const ushort* __restrict__ W1f,
    const ushort* __restrict__ W2f,
    const float* __restrict__ degf, const float* __restrict__ bias,
    const float* __restrict__ instats, const float* __restrict__ gammaL,
    const float* __restrict__ betaL, float invN,
    const int* __restrict__ row_ptr, const int* __restrict__ col,
    ushort* __restrict__ C, float* __restrict__ pstats, int N)
{
    constexpr int KR   = 192;
    constexpr int RS   = 200;               // padded row stride (ushorts)
    constexpr int SLAB = 64 * RS;           // 12800 ushorts per slab
    constexpr int NINSTR = SLAB / 512;      // 25 DMA instrs per slab
    constexpr int NKC  = 6, NCH = 12;

    __shared__ float sstat[2][HDIM];
    __shared__ __align__(16) ushort smem[2 * SLAB];
    const int tid  = threadIdx.x;
    const int wave = tid >> 6;              // 0..7
    const int lane = tid & 63;
    const int row0 = blockIdx.x * 64;
    const int m16 = lane & 15;
    const int g4  = lane >> 4;

    // ---- phase 1: stage A2 (own raw rows) into slab 1
    #pragma unroll
    for (int i = wave; i < NINSTR; i += 8) {
        int slotB = i * 1024 + lane * 16;
        int r   = slotB / (RS * 2);
        int off = slotB - r * (RS * 2);
        if (off >= KR * 2) off = KR * 2 - 16;
        int rr = row0 + r; if (rr >= N) rr = N - 1;
        gload_lds16(Hraw + (size_t)rr * KR + (off >> 1),
                    smem + SLAB + i * 512);
    }
    // BN coeffs computed while the DMA is in flight (only needs instats)
    if (tid < HDIM) {
        float mu  = instats[tid] * invN;
        float var = instats[HDIM + tid] * invN - mu * mu;
        float s = gammaL[tid] * rsqrtf(var + EPS);
        sstat[0][tid] = s;
        sstat[1][tid] = betaL[tid] - mu * s;
    }
    WAITV0();
    __syncthreads();                        // slab landed + coeffs visible

    const int r  = tid >> 3;                // 0..63: row
    const int q8 = tid & 7;                 // 0..7: 24-channel group
    // ---- phase 2b: apply relu(bn(.)) in place on A2 slab (own rows)
    {
        ushort* rowp = smem + SLAB + r * RS + q8 * 24;
        #pragma unroll
        for (int k = 0; k < 3; ++k) {
            uint4 hv = *(uint4*)(rowp + k * 8);
            uint hu[4] = {hv.x, hv.y, hv.z, hv.w};
            ushort oh[8];
            #pragma unroll
            for (int e = 0; e < 4; ++e) {
                int ch = q8 * 24 + k * 8 + e * 2;
                float v0 = h2f((ushort)(hu[e] & 0xffffu)) * sstat[0][ch]     + sstat[1][ch];
                float v1 = h2f((ushort)(hu[e] >> 16))     * sstat[0][ch + 1] + sstat[1][ch + 1];
                oh[2*e]   = f2h(fmaxf(v0, 0.f));
                oh[2*e+1] = f2h(fmaxf(v1, 0.f));
            }
            *(uint4*)(rowp + k * 8) = pack8(oh);
        }
    }
    // ---- phase 2c: gather neighbors -> A1 slab (8 thr/row, 24 ch each),
    //      unroll-4 with hoisted col loads: 4 edge-chains in flight.
    {
        float acg[24];
        #pragma unroll
        for (int i = 0; i < 24; ++i) acg[i] = 0.f;
        int rr = row0 + r;
        if (rr < N) {
            int j0 = row_ptr[rr], j1 = row_ptr[rr + 1];
            const ushort* hp = Hraw + q8 * 24;
            auto addrow = [&](const ushort* rp) {
                uint4 h0 = *(const uint4*)(rp);
                uint4 h1 = *(const uint4*)(rp + 8);
                uint4 h2 = *(const uint4*)(rp + 16);
                uint hu[12] = {h0.x,h0.y,h0.z,h0.w, h1.x,h1.y,h1.z,h1.w,
                               h2.x,h2.y,h2.z,h2.w};
                #pragma unroll
                for (int e = 0; e < 12; ++e) {
                    int ch = q8 * 24 + e * 2;
                    float v0 = h2f((ushort)(hu[e] & 0xffffu)) * sstat[0][ch]     + sstat[1][ch];
                    float v1 = h2f((ushort)(hu[e] >> 16))     * sstat[0][ch + 1] + sstat[1][ch + 1];
                    acg[e*2]     += fmaxf(v0, 0.f);
                    acg[e*2 + 1] += fmaxf(v1, 0.f);
                }
            };
            int j = j0;
            for (; j + 3 < j1; j += 4) {
                int s0 = col[j], s1 = col[j+1], s2 = col[j+2], s3 = col[j+3];
                const ushort* rp0 = hp + (size_t)s0 * KR;
                const ushort* rp1 = hp + (size_t)s1 * KR;
                const ushort* rp2 = hp + (size_t)s2 * KR;
                const ushort* rp3 = hp + (size_t)s3 * KR;
                addrow(rp0); addrow(rp1); addrow(rp2); addrow(rp3);
            }
            for (; j < j1; ++j)
                addrow(hp + (size_t)col[j] * KR);
        }
        ushort* dst = smem + r * RS + q8 * 24;
        #pragma unroll
        for (int ck = 0; ck < 3; ++ck) {
            ushort oh[8];
            #pragma unroll
            for (int e = 0; e < 8; ++e) oh[e] = f2h(acg[ck*8 + e]);
            *(uint4*)(dst + ck * 8) = pack8(oh);
        }
    }
    __syncthreads();                        // A1+A2 slabs ready
    if (tid < HDIM) { sstat[0][tid] = 0.f; sstat[1][tid] = 0.f; }

    // ---- phase 3: K-loop.  wave = rg(2) x cg(4): rows rg*32..+32, cols cg*48
    const int rg = wave >> 2;
    const int cg = wave & 3;

    auto loadB = [&](int c, half8* b) {
        bool ph = (c >= NKC);
        int kc = ph ? c - NKC : c;
        const ushort* Bp = (ph ? W2f : W1f) + (size_t)kc * 6144
                         + (size_t)(cg * 192 + lane) * 8;
        #pragma unroll
        for (int ct = 0; ct < 3; ++ct)
            b[ct] = *(const half8*)(Bp + ct * 512);
    };

    floatx4 acc[2][3];
    #pragma unroll
    for (int s = 0; s < 2; ++s)
        #pragma unroll
        for (int ct = 0; ct < 3; ++ct) acc[s][ct] = (floatx4){0.f, 0.f, 0.f, 0.f};

    half8 bA[3], bB[3];
    loadB(0, bA);
    #pragma unroll
    for (int c = 0; c < NCH; ++c) {
        if (c + 1 < NCH) loadB(c + 1, (c & 1) ? bA : bB);
        const int base = (c >= NKC) ? SLAB : 0;
        const int kc   = (c >= NKC) ? c - NKC : c;
        const ushort* aB = smem + base + (rg * 32 + m16) * RS + kc * 32 + g4 * 8;
        half8 a[2];
        #pragma unroll
        for (int s = 0; s < 2; ++s)
            a[s] = *(const half8*)(aB + s * 16 * RS);
        const half8* bu = (c & 1) ? bB : bA;
        #pragma unroll
        for (int ct = 0; ct < 3; ++ct)
            #pragma unroll
            for (int s = 0; s < 2; ++s)
                acc[s][ct] = __builtin_amdgcn_mfma_f32_16x16x32_f16(a[s], bu[ct], acc[s][ct], 0, 0, 0);
    }

    // ---- epilogue (deg*bias, stats, C-tile, burst)
    __syncthreads();
    #pragma unroll
    for (int ct = 0; ct < 3; ++ct) {
        int colc = cg * 48 + ct * 16 + m16;
        float bv = bias[colc];
        float lsum = 0.f, lsq = 0.f;
        #pragma unroll
        for (int s = 0; s < 2; ++s) {
            #pragma unroll
            for (int reg = 0; reg < 4; ++reg) {
                int rloc = rg * 32 + s * 16 + g4 * 4 + reg;
                int rr = row0 + rloc;
                int rrc = rr < N ? rr : N - 1;
                float v = acc[s][ct][reg] + degf[rrc] * bv;
                if (rr < N) { lsum += v; lsq += v * v; }
                smem[rloc * 200 + colc] = f2h(v);
            }
        }
        lsum += __shfl_xor(lsum, 16); lsum += __shfl_xor(lsum, 32);
        lsq  += __shfl_xor(lsq, 16);  lsq  += __shfl_xor(lsq, 32);
        if (g4 == 0) {
            atomicAdd(&sstat[0][colc], lsum);   // rg=0,1 waves both add
            atomicAdd(&sstat[1][colc], lsq);
        }
    }
    __syncthreads();
    {
        int rowsLeft = N - row0; if (rowsLeft > 64) rowsLeft = 64;
        int lim = rowsLeft * 24;
        ushort* Cb = C + (size_t)row0 * HDIM;
        #pragma unroll
        for (int k = 0; k < 3; ++k) {
            int u = tid + k * 512;
            if (u < lim) {
                int rr = u / 24;
                int c8 = (u - rr * 24) * 8;
                *(uint4*)(Cb + (size_t)u * 8) =
                    *(const uint4*)(smem + rr * 200 + c8);
            }
        }
    }
    if (tid < HDIM) {
        float* pb = pstats + (size_t)blockIdx.x * (2 * HDIM);
        pb[tid]        = sstat[0][tid];
        pb[HDIM + tid] = sstat[1][tid];
    }
}

// ---------------------------------------------------------------------------
// sum per-block BN partials: pbuf[nb][384] -> stats[384].
// ---------------------------------------------------------------------------
__global__ __launch_bounds__(256) void bn_reduce_k(
    const float* __restrict__ pbuf, float* __restrict__ stats, int nb)
{
    __shared__ float red[32][9];           // +1 pad
    int t  = threadIdx.x;
    int cl = t & 7;
    int s  = t >> 3;
    int c  = blockIdx.x * 8 + cl;
    float acc = 0.f;
    int b = s;
    for (; b + 96 < nb; b += 128) {
        float a0 = pbuf[(size_t)b * 384 + c];
        float a1 = pbuf[(size_t)(b + 32) * 384 + c];
        float a2 = pbuf[(size_t)(b + 64) * 384 + c];
        float a3 = pbuf[(size_t)(b + 96) * 384 + c];
        acc += a0 + a1 + a2 + a3;
    }
    for (; b < nb; b += 32)
        acc += pbuf[(size_t)b * 384 + c];
    red[s][cl] = acc;
    __syncthreads();
    if (t < 8) {
        float a = 0.f;
        #pragma unroll
        for (int i = 0; i < 32; ++i) a += red[i][t];
        stats[blockIdx.x * 8 + t] = a;
    }
}

// ---------------------------------------------------------------------------
// CSR construction from edge_dst
// ---------------------------------------------------------------------------
__global__ __launch_bounds__(256) void hist_k(
    const int* __restrict__ dst, int* __restrict__ deg, int E)
{
    int e = blockIdx.x * 256 + threadIdx.x;
    if (e < E) atomicAdd(&deg[dst[e]], 1);
}

__global__ __launch_bounds__(256) void block_sum_k(
    const int* __restrict__ deg, int* __restrict__ bsum, int N)
{
    __shared__ int s[256];
    int t = threadIdx.x;
    int n = blockIdx.x * 256 + t;
    s[t] = (n < N) ? deg[n] : 0;
    __syncthreads();
    for (int off = 128; off > 0; off >>= 1) {
        if (t < off) s[t] += s[t + off];
        __syncthreads();
    }
    if (t == 0) bsum[blockIdx.x] = s[0];
}

__global__ __launch_bounds__(512) void scan_bsum_k(int* __restrict__ bsum, int nb)
{
    __shared__ int s[512];
    int t = threadIdx.x;
    int v = (t < nb) ? bsum[t] : 0;
    s[t] = v;
    __syncthreads();
    for (int off = 1; off < 512; off <<= 1) {
        int u = (t >= off) ? s[t - off] : 0;
        __syncthreads();
        s[t] += u;
        __syncthreads();
    }
    if (t < nb) bsum[t] = s[t] - v;   // exclusive
}

__global__ __launch_bounds__(256) void row_ptr_k(
    const int* __restrict__ deg, const int* __restrict__ bsum,
    int* __restrict__ row_ptr, int* __restrict__ cursor,
    float* __restrict__ degf, int N, int E)
{
    __shared__ int s[256];
    int t = threadIdx.x;
    int n = blockIdx.x * 256 + t;
    int v = (n < N) ? deg[n] : 0;
    s[t] = v;
    __syncthreads();
    for (int off = 1; off < 256; off <<= 1) {
        int u = (t >= off) ? s[t - off] : 0;
        __syncthreads();
        s[t] += u;
        __syncthreads();
    }
    int ex = s[t] - v + bsum[blockIdx.x];
    if (n < N) {
        row_ptr[n] = ex;
        cursor[n]  = ex;
        degf[n]    = (float)v;
    }
    if (blockIdx.x == 0 && t == 0) row_ptr[N] = E;
}

__global__ __launch_bounds__(256) void fill_k(
    const int* __restrict__ src, const int* __restrict__ dst,
    int* __restrict__ cursor, int* __restrict__ col, int E)
{
    int e = blockIdx.x * 256 + threadIdx.x;
    if (e < E) {
        int p = atomicAdd(&cursor[dst[e]], 1);
        col[p] = src[e];
    }
}

// ---------------------------------------------------------------------------
// plain gather (layer 0, no BN): g[n] = sum_j x[col[j]]; row-major fp16.
// ---------------------------------------------------------------------------
__global__ __launch_bounds__(256) void gather_h_k(
    const ushort* __restrict__ xh, const int* __restrict__ row_ptr,
    const int* __restrict__ col, ushort* __restrict__ gh, int N, int K)
{
    int OC = K >> 3;
    int idx = blockIdx.x * 256 + threadIdx.x;
    if (idx >= N * OC) return;
    int n = idx / OC;
    int o = idx - n * OC;
    const ushort* hp = xh + o * 8;
    int j0 = row_ptr[n], j1 = row_ptr[n + 1];
    float acc[8] = {0.f,0.f,0.f,0.f,0.f,0.f,0.f,0.f};
    auto addrow = [&](uint4 hv) {
        uint hu[4] = {hv.x, hv.y, hv.z, hv.w};
        #pragma unroll
        for (int t = 0; t < 4; ++t) {
            acc[2*t]   += h2f((ushort)(hu[t] & 0xffffu));
            acc[2*t+1] += h2f((ushort)(hu[t] >> 16));
        }
    };
    int j = j0;
    for (; j + 3 < j1; j += 4) {
        int s0 = col[j], s1 = col[j+1], s2 = col[j+2], s3 = col[j+3];
        uint4 v0 = *(const uint4*)(hp + (size_t)s0 * K);
        uint4 v1 = *(const uint4*)(hp + (size_t)s1 * K);
        uint4 v2 = *(const uint4*)(hp + (size_t)s2 * K);
        uint4 v3 = *(const uint4*)(hp + (size_t)s3 * K);
        addrow(v0); addrow(v1); addrow(v2); addrow(v3);
    }
    for (; j < j1; ++j)
        addrow(*(const uint4*)(hp + (size_t)col[j] * K));
    ushort oh[8];
    #pragma unroll
    for (int t = 0; t < 8; ++t) oh[t] = f2h(acc[t]);
    *(uint4*)(gh + (size_t)n * K + o * 8) = pack8(oh);
}

// ---------------------------------------------------------------------------
// fused final-BN + mean-pool
// ---------------------------------------------------------------------------
__global__ __launch_bounds__(192) void pool_bn_k(
    const ushort* __restrict__ h, const float* __restrict__ stats,
    const float* __restrict__ gamma, const float* __restrict__ beta,
    float invN, const int* __restrict__ batch,
    ushort* __restrict__ gsh, int G, int N)
{
    __shared__ int bounds[2];
    int g = blockIdx.x;
    int c = threadIdx.x;
    if (c < 2) {
        int key = g + c;
        int lo = 0, hi = N;
        while (lo < hi) {
            int mid = (lo + hi) >> 1;
            if (batch[mid] < key) lo = mid + 1; else hi = mid;
        }
        bounds[c] = lo;
    }
    __syncthreads();
    int r0 = bounds[0], r1 = bounds[1];
    float mu  = stats[c] * invN;
    float var = stats[HDIM + c] * invN - mu * mu;
    float sc  = gamma[c] * rsqrtf(var + EPS);
    float sh  = beta[c] - mu * sc;
    const ushort* base = h + c;
    float s = 0.f;
    for (int r = r0; r < r1; ++r)
        s += fmaxf(h2f(base[(size_t)r * HDIM]) * sc + sh, 0.f);
    float m = s / fmaxf((float)(r1 - r0), 1.f);
    gsh[(size_t)g * HDIM + c] = f2h(m);
}

// ---------------------------------------------------------------------------
// out[g] = dot(g2[g,:], Wout) + bout ; g2 is fp16 row-major
// ---------------------------------------------------------------------------
__global__ __launch_bounds__(64) void out_dot_k(
    const ushort* __restrict__ g2h, const float* __restrict__ Wout,
    const float* __restrict__ bout, float* __restrict__ out, int G)
{
    int gi = blockIdx.x;
    int t = threadIdx.x;
    float s = 0.f;
    #pragma unroll
    for (int j = 0; j < 3; ++j) {
        int c = t + j * 64;
        s += h2f(g2h[(size_t)gi * HDIM + c]) * Wout[c];
    }
    #pragma unroll
    for (int off = 32; off > 0; off >>= 1) s += __shfl_down(s, off, 64);
    if (t == 0) out[gi] = s + bout[0];
}

// ---------------------------------------------------------------------------
extern "C" void kernel_launch(void* const* d_in, const int* in_sizes, int n_in,
                              void* d_out, int out_size, void* d_ws, size_t ws_size,
                              hipStream_t stream)
{
    const float* x      = (const float*)d_in[0];
    const int*   esrc   = (const int*)d_in[1];
    const int*   edst   = (const int*)d_in[2];
    const int*   batch  = (const int*)d_in[3];
    const float* Wrel0  = (const float*)d_in[4];
    const float* brel0  = (const float*)d_in[5];
    const float* Wroot0 = (const float*)d_in[6];
    const float* Wrel   = (const float*)d_in[7];
    const float* brel   = (const float*)d_in[8];
    const float* Wroot  = (const float*)d_in[9];
    const float* gamma  = (const float*)d_in[10];
    const float* beta   = (const float*)d_in[11];
    const float* Wh1    = (const float*)d_in[12];
    const float* bh1    = (const float*)d_in[13];
    const float* Wh2    = (const float*)d_in[14];
    const float* bh2    = (const float*)d_in[15];
    const float* Wout   = (const float*)d_in[16];
    const float* bout   = (const float*)d_in[17];
    float* out = (float*)d_out;

    const int N  = in_sizes[3];           // 100000
    const int E  = in_sizes[1];           // 400000
    const int K0 = in_sizes[0] / N;       // 32
    const int G  = out_size;              // 2000
    const int nBlocks = (N + 255) / 256;
    const float invN = 1.0f / (float)N;

    char* p = (char*)d_ws;
    auto carve = [&](size_t bytes) -> void* {
        void* r = (void*)p; p += (bytes + 255) & ~(size_t)255; return r;
    };
    ushort* bufa_h= (ushort*)carve((size_t)N * HDIM * 2);   // raw conv h (ping)
    ushort* bufb_h= (ushort*)carve((size_t)N * HDIM * 2);   // raw conv h (pong)
    ushort* xh    = (ushort*)carve((size_t)N * K0 * 2);     // layer0 input fp16
    ushort* gh    = (ushort*)carve((size_t)N * K0 * 2);     // layer0 gathered
    ushort* gsh   = (ushort*)carve((size_t)G * HDIM * 2);
    ushort* g1h   = (ushort*)carve((size_t)G * HDIM * 2);
    ushort* g2h   = (ushort*)carve((size_t)G * HDIM * 2);
    // deg + bnsums adjacent -> single memset
    int*    deg   = (int*)   carve((size_t)N * 4);
    float*  bnsums= (float*) carve(4 * 2 * HDIM * 4);
    size_t  zspan = (char*)(bnsums + 4 * 2 * HDIM) - (char*)deg;
    float*  degf  = (float*) carve((size_t)N * 4);
    int*    row_ptr=(int*)   carve((size_t)(N + 1) * 4);
    int*    cursor= (int*)   carve((size_t)N * 4);
    int*    col   = (int*)   carve((size_t)E * 4);
    int*    bsum  = (int*)   carve((size_t)nBlocks * 4);
    ushort* Wrel0f= (ushort*)carve((size_t)K0 * HDIM * 2);
    ushort* Wroot0f=(ushort*)carve((size_t)K0 * HDIM * 2);
    ushort* Wrelf = (ushort*)carve((size_t)3 * HDIM * HDIM * 2);
    ushort* Wrootf= (ushort*)carve((size_t)3 * HDIM * HDIM * 2);
    ushort* Wh1f  = (ushort*)carve((size_t)HDIM * HDIM * 2);
    ushort* Wh2f  = (ushort*)carve((size_t)HDIM * HDIM * 2);

    dim3 b256(256);
    const int eBlocks = (E + 255) / 256;
    const int gemmN = (N + 63) / 64;
    const int gemmG = (G + 63) / 64;

    float*  pbuf  = (float*) carve((size_t)gemmN * 2 * HDIM * 4);  // BN partials

    // ---- merged weight prep (1 launch)
    {
        PrepArgs a;
        int t0 = (K0 >> 5) * 12 * 64;        // 768
        int t1 = (HDIM >> 5) * 12 * 64;      // 4608
        a.src[0] = Wrel0;  a.dst[0] = Wrel0f;  a.K[0] = K0;
        a.src[1] = Wroot0; a.dst[1] = Wroot0f; a.K[1] = K0;
        a.src[2] = Wrel;   a.dst[2] = Wrelf;   a.K[2] = HDIM;
        a.src[3] = Wroot;  a.dst[3] = Wrootf;  a.K[3] = HDIM;
        a.src[4] = Wh1;    a.dst[4] = Wh1f;    a.K[4] = HDIM;
        a.src[5] = Wh2;    a.dst[5] = Wh2f;    a.K[5] = HDIM;
        a.off[0] = 0;
        a.off[1] = a.off[0] + t0;
        a.off[2] = a.off[1] + t0;
        a.off[3] = a.off[2] + 3 * t1;
        a.off[4] = a.off[3] + 3 * t1;
        a.off[5] = a.off[4] + t1;
        a.off[6] = a.off[5] + t1;
        prep_all_k<<<(a.off[6] + 255) / 256, b256, 0, stream>>>(a);
    }
    // x -> row-major fp16 [N][32]
    conv_half_k<<<((N * (K0 >> 3)) + 255) / 256, b256, 0, stream>>>(x, xh, N, K0);

    // ---- CSR build
    hipMemsetAsync(deg, 0, zspan, stream);   // zeros deg + bnsums
    hist_k<<<eBlocks, b256, 0, stream>>>(edst, deg, E);
    block_sum_k<<<nBlocks, b256, 0, stream>>>(deg, bsum, N);
    scan_bsum_k<<<1, dim3(512), 0, stream>>>(bsum, nBlocks);
    row_ptr_k<<<nBlocks, b256, 0, stream>>>(deg, bsum, row_ptr, cursor, degf, N, E);
    fill_k<<<eBlocks, b256, 0, stream>>>(esrc, edst, cursor, col, E);

    // ---- layer 0 (input x, no input BN): K=32 dual -> NKC=1; writes bufa
    gather_h_k<<<((N * (K0 >> 3)) + 255) / 256, b256, 0, stream>>>(
        xh, row_ptr, col, gh, N, K0);
    gemm_mfma_k<true, false, true, true, 1><<<gemmN, b256, 0, stream>>>(
        gh, Wrel0f, xh, Wroot0f, degf, brel0, bufa_h, pbuf, N, K0);
    bn_reduce_k<<<48, b256, 0, stream>>>(pbuf, bnsums, gemmN);

    // ---- layers 1..3: FUSED gather+BN+GEMM (512 thr), ping-pong bufa<->bufb
    ushort* rd = bufa_h;
    ushort* wr = bufb_h;
    for (int l = 1; l < 4; ++l) {
        const ushort* Wrf = Wrelf  + (size_t)(l - 1) * HDIM * HDIM;
        const ushort* Wtf = Wrootf + (size_t)(l - 1) * HDIM * HDIM;
        const float*  br  = brel   + (size_t)(l - 1) * HDIM;
        const float*  st  = bnsums + (size_t)(l - 1) * 2 * HDIM;
        const float*  gm  = gamma  + (size_t)(l - 1) * HDIM;
        const float*  bt  = beta   + (size_t)(l - 1) * HDIM;
        gemm_fused_k<<<gemmN, dim3(512), 0, stream>>>(
            rd, Wrf, Wtf, degf, br, st, gm, bt, invN,
            row_ptr, col, wr, pbuf, N);
        bn_reduce_k<<<48, b256, 0, stream>>>(pbuf, bnsums + l * 2 * HDIM, gemmN);
        ushort* tmp = rd; rd = wr; wr = tmp;
    }
    // after 3 layers: rd holds the final raw h (bufb)

    // ---- fused final BN + mean pool -> fp16 row-major head input
    pool_bn_k<<<G, dim3(192), 0, stream>>>(
        rd, bnsums + 3 * 2 * HDIM, gamma + 3 * HDIM, beta + 3 * HDIM,
        invN, batch, gsh, G, N);

    // ---- head MLP (MFMA path, row-major fp16 end-to-end; K=192 -> NKC=6)
    gemm_mfma_k<false, true, false, false, 6><<<gemmG, b256, 0, stream>>>(
        gsh, Wh1f, nullptr, nullptr, nullptr, bh1, g1h, nullptr, G, HDIM);
    gemm_mfma_k<false, false, false, false, 6><<<gemmG, b256, 0, stream>>>(
        g1h, Wh2f, nullptr, nullptr, nullptr, bh2, g2h, nullptr, G, HDIM);
    out_dot_k<<<G, dim3(64), 0, stream>>>(g2h, Wout, bout, out, G);
}

// Round 14
// 433.020 us; speedup vs baseline: 1.9503x; 1.2256x over previous
//
#include <hip/hip_runtime.h>

#define HDIM 192
#define EPS 1e-5f

typedef __attribute__((ext_vector_type(8))) _Float16 half8;
typedef __attribute__((ext_vector_type(4))) float floatx4;

__device__ __forceinline__ float h2f(ushort u) {
    union { ushort u; _Float16 h; } c; c.u = u; return (float)c.h;
}
__device__ __forceinline__ ushort f2h(float x) {
    _Float16 h = (_Float16)x;           // RTN
    union { _Float16 h; ushort u; } c; c.h = h; return c.u;
}
__device__ __forceinline__ uint4 pack8(const ushort* h) {
    uint4 p;
    p.x = h[0] | ((uint)h[1] << 16); p.y = h[2] | ((uint)h[3] << 16);
    p.z = h[4] | ((uint)h[5] << 16); p.w = h[6] | ((uint)h[7] << 16);
    return p;
}

// async global->LDS DMA, 16B per lane; LDS dest = wave-uniform base + lane*16,
// global source is PER-LANE (guide m104/m173).
__device__ __forceinline__ void gload_lds16(const ushort* g, ushort* l) {
    __builtin_amdgcn_global_load_lds(
        (const __attribute__((address_space(1))) unsigned int*)g,
        (__attribute__((address_space(3))) unsigned int*)l, 16, 0, 0);
}

#define WAITV0() asm volatile("s_waitcnt vmcnt(0)" ::: "memory")

// Activations are ROW-MAJOR fp16 [R][K].

// ---------------------------------------------------------------------------
// Merged weight prep: all 10 matrices in ONE launch.
// ---------------------------------------------------------------------------
struct PrepArgs {
    const float* src[6];
    ushort*      dst[6];
    int K[6];
    int off[7];       // thread offsets (per entry: nmat*(K/32)*12*64)
};

__global__ __launch_bounds__(256) void prep_all_k(PrepArgs a)
{
    int idx = blockIdx.x * 256 + threadIdx.x;
    if (idx >= a.off[6]) return;
    int i = 0;
    #pragma unroll
    for (int t = 1; t < 6; ++t) if (idx >= a.off[t]) i = t;
    int r = idx - a.off[i];
    int K = a.K[i];
    int perMat = (K >> 5) * 12 * 64;
    int mat = r / perMat;
    r -= mat * perMat;
    int lane = r & 63;
    int ct = (r >> 6) % 12;
    int kc = r / (12 * 64);
    int col = ct * 16 + (lane & 15);
    int kb  = kc * 32 + (lane >> 4) * 8;
    const float* Wm = a.src[i] + (size_t)mat * K * HDIM;
    ushort* base = a.dst[i] + (size_t)mat * K * HDIM;
    size_t o = (size_t)kc * 6144 + (size_t)(ct * 64 + lane) * 8;
    #pragma unroll
    for (int j = 0; j < 8; ++j)
        base[o + j] = f2h(Wm[(size_t)(kb + j) * HDIM + col]);
}

// ---------------------------------------------------------------------------
// fp32 row-major [R, C] -> fp16 row-major. One thread per 8 channels.
// ---------------------------------------------------------------------------
__global__ __launch_bounds__(256) void conv_half_k(
    const float* __restrict__ src, ushort* __restrict__ dst, int R, int C)
{
    int OC = C >> 3;
    int idx = blockIdx.x * 256 + threadIdx.x;
    if (idx >= R * OC) return;
    int r = idx / OC;
    int o = idx - r * OC;
    float4 v0 = ((const float4*)(src + (size_t)r * C + o * 8))[0];
    float4 v1 = ((const float4*)(src + (size_t)r * C + o * 8))[1];
    float v[8] = {v0.x, v0.y, v0.z, v0.w, v1.x, v1.y, v1.z, v1.w};
    ushort h[8];
    #pragma unroll
    for (int t = 0; t < 8; ++t) h[t] = f2h(v[t]);
    *(uint4*)(dst + (size_t)r * C + o * 8) = pack8(h);
}

// ---------------------------------------------------------------------------
// MFMA GEMM (layer0 + head): slab staging, barrier-free K-loop, LDS C-tile,
// per-block BN partials (no global atomics).  256 thr / 4 waves.
// ---------------------------------------------------------------------------
template<bool DUAL, bool RELU, bool DEG, bool STATS, int NKC>
__global__ __launch_bounds__(256, 3) void gemm_mfma_k(
    const ushort* __restrict__ A1h, const ushort* __restrict__ W1f,
    const ushort* __restrict__ A2h, const ushort* __restrict__ W2f,
    const float* __restrict__ degf, const float* __restrict__ bias,
    ushort* __restrict__ C, float* __restrict__ pstats, int N, int K)
{
    constexpr int KR   = NKC * 32;          // A row length (ushorts)
    constexpr int RS   = KR + 8;            // padded LDS row stride (ushorts)
    constexpr int SLAB = 64 * RS;           // ushorts per slab
    constexpr int NINSTR = SLAB / 512;      // wave DMA instrs per slab (1KB each)
    constexpr int NCH  = DUAL ? 2 * NKC : NKC;
    constexpr int SMEMU = ((DUAL ? 2 * SLAB : SLAB) > 12800)
                            ? (DUAL ? 2 * SLAB : SLAB) : 12800;  // C-tile needs 64*200

    __shared__ float sstat[2][HDIM];
    __shared__ __align__(16) ushort smem[SMEMU];
    const int tid  = threadIdx.x;
    const int wave = tid >> 6;      // 0..3 = column group (48 cols each)
    const int lane = tid & 63;
    const int row0 = blockIdx.x * 64;
    const int m16 = lane & 15;
    const int g4  = lane >> 4;

    if (STATS && tid < HDIM) { sstat[0][tid] = 0.f; sstat[1][tid] = 0.f; }

    // ---- slab staging: linear LDS slots -> per-lane (row, offset) source
    auto stage = [&](const ushort* Ab, int slabOff) {
        #pragma unroll
        for (int i = wave; i < NINSTR; i += 4) {
            int slotB = i * 1024 + lane * 16;        // byte offset in slab
            int r   = slotB / (RS * 2);
            int off = slotB - r * (RS * 2);          // byte within padded row
            if (off >= KR * 2) off = KR * 2 - 16;    // pad slot: dup last 16B
            int rr = row0 + r; if (rr >= N) rr = N - 1;
            gload_lds16(Ab + (size_t)rr * KR + (off >> 1),
                        smem + slabOff + i * 512);   // wave-uniform dest base
        }
    };

    stage(A1h, 0);
    if constexpr (DUAL) stage(A2h, SLAB);
    WAITV0();
    __builtin_amdgcn_s_barrier();            // all waves' slab quarters landed
    __builtin_amdgcn_sched_barrier(0);

    auto loadB = [&](int c, half8* b) {
        bool ph = DUAL && (c >= NKC);
        int kc = ph ? c - NKC : c;
        const ushort* Bp = (ph ? W2f : W1f) + (size_t)kc * 6144
                         + (size_t)(wave * 192 + lane) * 8;
        #pragma unroll
        for (int ct = 0; ct < 3; ++ct)
            b[ct] = *(const half8*)(Bp + ct * 512);
    };

    floatx4 acc[4][3];
    #pragma unroll
    for (int s = 0; s < 4; ++s)
        #pragma unroll
        for (int ct = 0; ct < 3; ++ct) acc[s][ct] = (floatx4){0.f, 0.f, 0.f, 0.f};

    // ---- K-loop: pure LDS + MFMA, no barriers, B register-dbuf from L2
    half8 bA[3], bB[3];
    loadB(0, bA);
    #pragma unroll
    for (int c = 0; c < NCH; ++c) {
        if (c + 1 < NCH) loadB(c + 1, (c & 1) ? bA : bB);
        const int base = (DUAL && c >= NKC) ? SLAB : 0;
        const int kc   = (DUAL && c >= NKC) ? c - NKC : c;
        const ushort* aB = smem + base + m16 * RS + kc * 32 + g4 * 8;
        half8 a[4];
        #pragma unroll
        for (int s = 0; s < 4; ++s)
            a[s] = *(const half8*)(aB + s * 16 * RS);
        const half8* bu = (c & 1) ? bB : bA;
        #pragma unroll
        for (int ct = 0; ct < 3; ++ct)
            #pragma unroll
            for (int s = 0; s < 4; ++s)
                acc[s][ct] = __builtin_amdgcn_mfma_f32_16x16x32_f16(a[s], bu[ct], acc[s][ct], 0, 0, 0);
    }

    // ---- epilogue: acc -> LDS C-tile (reuses slab0) -> linear global burst
    __syncthreads();                // all waves done reading slabs
    // C/D layout col=lane&15, row=(lane>>4)*4+reg  [m89]
    #pragma unroll
    for (int ct = 0; ct < 3; ++ct) {
        int col = wave * 48 + ct * 16 + m16;
        float bv = bias ? bias[col] : 0.f;
        float lsum = 0.f, lsq = 0.f;
        #pragma unroll
        for (int s = 0; s < 4; ++s) {
            #pragma unroll
            for (int reg = 0; reg < 4; ++reg) {
                int rloc = s * 16 + g4 * 4 + reg;
                int rr = row0 + rloc;
                int rrc = rr < N ? rr : N - 1;
                float v = acc[s][ct][reg] + (DEG ? degf[rrc] * bv : bv);
                if (STATS && rr < N) { lsum += v; lsq += v * v; }
                if (RELU) v = fmaxf(v, 0.f);
                smem[rloc * 200 + col] = f2h(v);
            }
        }
        if (STATS) {
            lsum += __shfl_xor(lsum, 16); lsum += __shfl_xor(lsum, 32);
            lsq  += __shfl_xor(lsq, 16);  lsq  += __shfl_xor(lsq, 32);
            if (g4 == 0) {
                atomicAdd(&sstat[0][col], lsum);   // LDS atomics: cheap
                atomicAdd(&sstat[1][col], lsq);
            }
        }
    }
    __syncthreads();                // C-tile + sstat complete
    {
        int rowsLeft = N - row0; if (rowsLeft > 64) rowsLeft = 64;
        int lim = rowsLeft * 24;    // uint4 count (24 per row)
        ushort* Cb = C + (size_t)row0 * HDIM;
        #pragma unroll
        for (int k = 0; k < 6; ++k) {
            int u = tid + k * 256;
            if (u < lim) {
                int r  = u / 24;
                int c8 = (u - r * 24) * 8;
                *(uint4*)(Cb + (size_t)u * 8) =
                    *(const uint4*)(smem + r * 200 + c8);
            }
        }
    }
    if (STATS) {
        if (tid < HDIM) {
            float* pb = pstats + (size_t)blockIdx.x * (2 * HDIM);
            pb[tid]        = sstat[0][tid];
            pb[HDIM + tid] = sstat[1][tid];
        }
    }
}

// ---------------------------------------------------------------------------
// FUSED layer kernel (layers 1..3), 512 thr / 8 waves, DUAL-SLAB (R10
// structure; proven 77us, VGPR 64, no spill).  Gather stays ROLLED --
// R11/R12/R13 all proved hipcc spills rather than allocate >64 VGPRs for
// wider gather state.  Only change vs R10: the col index is prefetched one
// edge ahead (1 extra int), removing the ~200cy col-load from the per-edge
// critical path.
//  phase 1: stage own-row raw-h slab (A2) via global_load_lds.
//  phase 2: BN coeffs (under DMA); BN apply in LDS on A2; gather neighbors
//           (8 thr/row x 24 ch) -> A1 slab in LDS.
//  phase 3: barrier-free 12-chunk K-loop; 8 waves = 2 row-groups x 4
//           col-groups, wave tile 32x48, acc[2][3]; epilogue w/ BN partials.
// Output C MUST differ from Hraw (ping-pong).
// ---------------------------------------------------------------------------
__global__ __launch_bounds__(512, 4) void gemm_fused_k(
    const ushort* __restrict__ Hraw, const ushort* __restrict__ W1f,
    const ushort* __restrict__ W2f,
    const float* __restrict__ degf, const float* __restrict__ bias,
    const float* __restrict__ instats, const float* __restrict__ gammaL,
    const float* __restrict__ betaL, float invN,
    const int* __restrict__ row_ptr, const int* __restrict__ col,
    ushort* __restrict__ C, float* __restrict__ pstats, int N)
{
    constexpr int KR   = 192;
    constexpr int RS   = 200;               // padded row stride (ushorts)
    constexpr int SLAB = 64 * RS;           // 12800 ushorts per slab
    constexpr int NINSTR = SLAB / 512;      // 25 DMA instrs per slab
    constexpr int NKC  = 6, NCH = 12;

    __shared__ float sstat[2][HDIM];
    __shared__ __align__(16) ushort smem[2 * SLAB];
    const int tid  = threadIdx.x;
    const int wave = tid >> 6;              // 0..7
    const int lane = tid & 63;
    const int row0 = blockIdx.x * 64;
    const int m16 = lane & 15;
    const int g4  = lane >> 4;

    // ---- phase 1: stage A2 (own raw rows) into slab 1
    #pragma unroll
    for (int i = wave; i < NINSTR; i += 8) {
        int slotB = i * 1024 + lane * 16;
        int r   = slotB / (RS * 2);
        int off = slotB - r * (RS * 2);
        if (off >= KR * 2) off = KR * 2 - 16;
        int rr = row0 + r; if (rr >= N) rr = N - 1;
        gload_lds16(Hraw + (size_t)rr * KR + (off >> 1),
                    smem + SLAB + i * 512);
    }
    // BN coeffs computed while the DMA is in flight (only needs instats)
    if (tid < HDIM) {
        float mu  = instats[tid] * invN;
        float var = instats[HDIM + tid] * invN - mu * mu;
        float s = gammaL[tid] * rsqrtf(var + EPS);
        sstat[0][tid] = s;
        sstat[1][tid] = betaL[tid] - mu * s;
    }
    WAITV0();
    __syncthreads();                        // slab landed + coeffs visible

    const int r  = tid >> 3;                // 0..63: row
    const int q8 = tid & 7;                 // 0..7: 24-channel group
    // ---- phase 2b: apply relu(bn(.)) in place on A2 slab (own rows)
    {
        ushort* rowp = smem + SLAB + r * RS + q8 * 24;
        #pragma unroll
        for (int k = 0; k < 3; ++k) {
            uint4 hv = *(uint4*)(rowp + k * 8);
            uint hu[4] = {hv.x, hv.y, hv.z, hv.w};
            ushort oh[8];
            #pragma unroll
            for (int e = 0; e < 4; ++e) {
                int ch = q8 * 24 + k * 8 + e * 2;
                float v0 = h2f((ushort)(hu[e] & 0xffffu)) * sstat[0][ch]     + sstat[1][ch];
                float v1 = h2f((ushort)(hu[e] >> 16))     * sstat[0][ch + 1] + sstat[1][ch + 1];
                oh[2*e]   = f2h(fmaxf(v0, 0.f));
                oh[2*e+1] = f2h(fmaxf(v1, 0.f));
            }
            *(uint4*)(rowp + k * 8) = pack8(oh);
        }
    }
    // ---- phase 2c: gather neighbors -> A1 slab (8 thr/row, 24 ch each);
    //      ROLLED loop (wider state spills -- R11/R12/R13), col prefetched
    //      one edge ahead so the col load overlaps the row processing.
    {
        float acg[24];
        #pragma unroll
        for (int i = 0; i < 24; ++i) acg[i] = 0.f;
        int rr = row0 + r;
        if (rr < N) {
            int j0 = row_ptr[rr], j1 = row_ptr[rr + 1];
            const ushort* hp = Hraw + q8 * 24;
            int sNext = (j0 < j1) ? col[j0] : 0;
            for (int j = j0; j < j1; ++j) {
                int s = sNext;
                if (j + 1 < j1) sNext = col[j + 1];
                const ushort* rp = hp + (size_t)s * KR;
                uint4 h0 = *(const uint4*)(rp);
                uint4 h1 = *(const uint4*)(rp + 8);
                uint4 h2 = *(const uint4*)(rp + 16);
                uint hu[12] = {h0.x,h0.y,h0.z,h0.w, h1.x,h1.y,h1.z,h1.w,
                               h2.x,h2.y,h2.z,h2.w};
                #pragma unroll
                for (int e = 0; e < 12; ++e) {
                    int ch = q8 * 24 + e * 2;
                    float v0 = h2f((ushort)(hu[e] & 0xffffu)) * sstat[0][ch]     + sstat[1][ch];
                    float v1 = h2f((ushort)(hu[e] >> 16))     * sstat[0][ch + 1] + sstat[1][ch + 1];
                    acg[e*2]     += fmaxf(v0, 0.f);
                    acg[e*2 + 1] += fmaxf(v1, 0.f);
                }
            }
        }
        ushort* dst = smem + r * RS + q8 * 24;
        #pragma unroll
        for (int ck = 0; ck < 3; ++ck) {
            ushort oh[8];
            #pragma unroll
            for (int e = 0; e < 8; ++e) oh[e] = f2h(acg[ck*8 + e]);
            *(uint4*)(dst + ck * 8) = pack8(oh);
        }
    }
    __syncthreads();                        // A1+A2 slabs ready
    if (tid < HDIM) { sstat[0][tid] = 0.f; sstat[1][tid] = 0.f; }

    // ---- phase 3: K-loop.  wave = rg(2) x cg(4): rows rg*32..+32, cols cg*48
    const int rg = wave >> 2;
    const int cg = wave & 3;

    auto loadB = [&](int c, half8* b) {
        bool ph = (c >= NKC);
        int kc = ph ? c - NKC : c;
        const ushort* Bp = (ph ? W2f : W1f) + (size_t)kc * 6144
                         + (size_t)(cg * 192 + lane) * 8;
        #pragma unroll
        for (int ct = 0; ct < 3; ++ct)
            b[ct] = *(const half8*)(Bp + ct * 512);
    };

    floatx4 acc[2][3];
    #pragma unroll
    for (int s = 0; s < 2; ++s)
        #pragma unroll
        for (int ct = 0; ct < 3; ++ct) acc[s][ct] = (floatx4){0.f, 0.f, 0.f, 0.f};

    half8 bA[3], bB[3];
    loadB(0, bA);
    #pragma unroll
    for (int c = 0; c < NCH; ++c) {
        if (c + 1 < NCH) loadB(c + 1, (c & 1) ? bA : bB);
        const int base = (c >= NKC) ? SLAB : 0;
        const int kc   = (c >= NKC) ? c - NKC : c;
        const ushort* aB = smem + base + (rg * 32 + m16) * RS + kc * 32 + g4 * 8;
        half8 a[2];
        #pragma unroll
        for (int s = 0; s < 2; ++s)
            a[s] = *(const half8*)(aB + s * 16 * RS);
        const half8* bu = (c & 1) ? bB : bA;
        #pragma unroll
        for (int ct = 0; ct < 3; ++ct)
            #pragma unroll
            for (int s = 0; s < 2; ++s)
                acc[s][ct] = __builtin_amdgcn_mfma_f32_16x16x32_f16(a[s], bu[ct], acc[s][ct], 0, 0, 0);
    }

    // ---- epilogue (deg*bias, stats, C-tile, burst)
    __syncthreads();
    #pragma unroll
    for (int ct = 0; ct < 3; ++ct) {
        int colc = cg * 48 + ct * 16 + m16;
        float bv = bias[colc];
        float lsum = 0.f, lsq = 0.f;
        #pragma unroll
        for (int s = 0; s < 2; ++s) {
            #pragma unroll
            for (int reg = 0; reg < 4; ++reg) {
                int rloc = rg * 32 + s * 16 + g4 * 4 + reg;
                int rr = row0 + rloc;
                int rrc = rr < N ? rr : N - 1;
                float v = acc[s][ct][reg] + degf[rrc] * bv;
                if (rr < N) { lsum += v; lsq += v * v; }
                smem[rloc * 200 + colc] = f2h(v);
            }
        }
        lsum += __shfl_xor(lsum, 16); lsum += __shfl_xor(lsum, 32);
        lsq  += __shfl_xor(lsq, 16);  lsq  += __shfl_xor(lsq, 32);
        if (g4 == 0) {
            atomicAdd(&sstat[0][colc], lsum);   // rg=0,1 waves both add
            atomicAdd(&sstat[1][colc], lsq);
        }
    }
    __syncthreads();
    {
        int rowsLeft = N - row0; if (rowsLeft > 64) rowsLeft = 64;
        int lim = rowsLeft * 24;
        ushort* Cb = C + (size_t)row0 * HDIM;
        #pragma unroll
        for (int k = 0; k < 3; ++k) {
            int u = tid + k * 512;
            if (u < lim) {
                int rr = u / 24;
                int c8 = (u - rr * 24) * 8;
                *(uint4*)(Cb + (size_t)u * 8) =
                    *(const uint4*)(smem + rr * 200 + c8);
            }
        }
    }
    if (tid < HDIM) {
        float* pb = pstats + (size_t)blockIdx.x * (2 * HDIM);
        pb[tid]        = sstat[0][tid];
        pb[HDIM + tid] = sstat[1][tid];
    }
}

// ---------------------------------------------------------------------------
// sum per-block BN partials: pbuf[nb][384] -> stats[384].
// ---------------------------------------------------------------------------
__global__ __launch_bounds__(256) void bn_reduce_k(
    const float* __restrict__ pbuf, float* __restrict__ stats, int nb)
{
    __shared__ float red[32][9];           // +1 pad
    int t  = threadIdx.x;
    int cl = t & 7;
    int s  = t >> 3;
    int c  = blockIdx.x * 8 + cl;
    float acc = 0.f;
    int b = s;
    for (; b + 96 < nb; b += 128) {
        float a0 = pbuf[(size_t)b * 384 + c];
        float a1 = pbuf[(size_t)(b + 32) * 384 + c];
        float a2 = pbuf[(size_t)(b + 64) * 384 + c];
        float a3 = pbuf[(size_t)(b + 96) * 384 + c];
        acc += a0 + a1 + a2 + a3;
    }
    for (; b < nb; b += 32)
        acc += pbuf[(size_t)b * 384 + c];
    red[s][cl] = acc;
    __syncthreads();
    if (t < 8) {
        float a = 0.f;
        #pragma unroll
        for (int i = 0; i < 32; ++i) a += red[i][t];
        stats[blockIdx.x * 8 + t] = a;
    }
}

// ---------------------------------------------------------------------------
// CSR construction from edge_dst
// ---------------------------------------------------------------------------
__global__ __launch_bounds__(256) void hist_k(
    const int* __restrict__ dst, int* __restrict__ deg, int E)
{
    int e = blockIdx.x * 256 + threadIdx.x;
    if (e < E) atomicAdd(&deg[dst[e]], 1);
}

__global__ __launch_bounds__(256) void block_sum_k(
    const int* __restrict__ deg, int* __restrict__ bsum, int N)
{
    __shared__ int s[256];
    int t = threadIdx.x;
    int n = blockIdx.x * 256 + t;
    s[t] = (n < N) ? deg[n] : 0;
    __syncthreads();
    for (int off = 128; off > 0; off >>= 1) {
        if (t < off) s[t] += s[t + off];
        __syncthreads();
    }
    if (t == 0) bsum[blockIdx.x] = s[0];
}

__global__ __launch_bounds__(512) void scan_bsum_k(int* __restrict__ bsum, int nb)
{
    __shared__ int s[512];
    int t = threadIdx.x;
    int v = (t < nb) ? bsum[t] : 0;
    s[t] = v;
    __syncthreads();
    for (int off = 1; off < 512; off <<= 1) {
        int u = (t >= off) ? s[t - off] : 0;
        __syncthreads();
        s[t] += u;
        __syncthreads();
    }
    if (t < nb) bsum[t] = s[t] - v;   // exclusive
}

__global__ __launch_bounds__(256) void row_ptr_k(
    const int* __restrict__ deg, const int* __restrict__ bsum,
    int* __restrict__ row_ptr, int* __restrict__ cursor,
    float* __restrict__ degf, int N, int E)
{
    __shared__ int s[256];
    int t = threadIdx.x;
    int n = blockIdx.x * 256 + t;
    int v = (n < N) ? deg[n] : 0;
    s[t] = v;
    __syncthreads();
    for (int off = 1; off < 256; off <<= 1) {
        int u = (t >= off) ? s[t - off] : 0;
        __syncthreads();
        s[t] += u;
        __syncthreads();
    }
    int ex = s[t] - v + bsum[blockIdx.x];
    if (n < N) {
        row_ptr[n] = ex;
        cursor[n]  = ex;
        degf[n]    = (float)v;
    }
    if (blockIdx.x == 0 && t == 0) row_ptr[N] = E;
}

__global__ __launch_bounds__(256) void fill_k(
    const int* __restrict__ src, const int* __restrict__ dst,
    int* __restrict__ cursor, int* __restrict__ col, int E)
{
    int e = blockIdx.x * 256 + threadIdx.x;
    if (e < E) {
        int p = atomicAdd(&cursor[dst[e]], 1);
        col[p] = src[e];
    }
}

// ---------------------------------------------------------------------------
// plain gather (layer 0, no BN): g[n] = sum_j x[col[j]]; row-major fp16.
// ---------------------------------------------------------------------------
__global__ __launch_bounds__(256) void gather_h_k(
    const ushort* __restrict__ xh, const int* __restrict__ row_ptr,
    const int* __restrict__ col, ushort* __restrict__ gh, int N, int K)
{
    int OC = K >> 3;
    int idx = blockIdx.x * 256 + threadIdx.x;
    if (idx >= N * OC) return;
    int n = idx / OC;
    int o = idx - n * OC;
    const ushort* hp = xh + o * 8;
    int j0 = row_ptr[n], j1 = row_ptr[n + 1];
    float acc[8] = {0.f,0.f,0.f,0.f,0.f,0.f,0.f,0.f};
    auto addrow = [&](uint4 hv) {
        uint hu[4] = {hv.x, hv.y, hv.z, hv.w};
        #pragma unroll
        for (int t = 0; t < 4; ++t) {
            acc[2*t]   += h2f((ushort)(hu[t] & 0xffffu));
            acc[2*t+1] += h2f((ushort)(hu[t] >> 16));
        }
    };
    int j = j0;
    for (; j + 3 < j1; j += 4) {
        int s0 = col[j], s1 = col[j+1], s2 = col[j+2], s3 = col[j+3];
        uint4 v0 = *(const uint4*)(hp + (size_t)s0 * K);
        uint4 v1 = *(const uint4*)(hp + (size_t)s1 * K);
        uint4 v2 = *(const uint4*)(hp + (size_t)s2 * K);
        uint4 v3 = *(const uint4*)(hp + (size_t)s3 * K);
        addrow(v0); addrow(v1); addrow(v2); addrow(v3);
    }
    for (; j < j1; ++j)
        addrow(*(const uint4*)(hp + (size_t)col[j] * K));
    ushort oh[8];
    #pragma unroll
    for (int t = 0; t < 8; ++t) oh[t] = f2h(acc[t]);
    *(uint4*)(gh + (size_t)n * K + o * 8) = pack8(oh);
}

// ---------------------------------------------------------------------------
// fused final-BN + mean-pool
// ---------------------------------------------------------------------------
__global__ __launch_bounds__(192) void pool_bn_k(
    const ushort* __restrict__ h, const float* __restrict__ stats,
    const float* __restrict__ gamma, const float* __restrict__ beta,
    float invN, const int* __restrict__ batch,
    ushort* __restrict__ gsh, int G, int N)
{
    __shared__ int bounds[2];
    int g = blockIdx.x;
    int c = threadIdx.x;
    if (c < 2) {
        int key = g + c;
        int lo = 0, hi = N;
        while (lo < hi) {
            int mid = (lo + hi) >> 1;
            if (batch[mid] < key) lo = mid + 1; else hi = mid;
        }
        bounds[c] = lo;
    }
    __syncthreads();
    int r0 = bounds[0], r1 = bounds[1];
    float mu  = stats[c] * invN;
    float var = stats[HDIM + c] * invN - mu * mu;
    float sc  = gamma[c] * rsqrtf(var + EPS);
    float sh  = beta[c] - mu * sc;
    const ushort* base = h + c;
    float s = 0.f;
    for (int r = r0; r < r1; ++r)
        s += fmaxf(h2f(base[(size_t)r * HDIM]) * sc + sh, 0.f);
    float m = s / fmaxf((float)(r1 - r0), 1.f);
    gsh[(size_t)g * HDIM + c] = f2h(m);
}

// ---------------------------------------------------------------------------
// out[g] = dot(g2[g,:], Wout) + bout ; g2 is fp16 row-major
// ---------------------------------------------------------------------------
__global__ __launch_bounds__(64) void out_dot_k(
    const ushort* __restrict__ g2h, const float* __restrict__ Wout,
    const float* __restrict__ bout, float* __restrict__ out, int G)
{
    int gi = blockIdx.x;
    int t = threadIdx.x;
    float s = 0.f;
    #pragma unroll
    for (int j = 0; j < 3; ++j) {
        int c = t + j * 64;
        s += h2f(g2h[(size_t)gi * HDIM + c]) * Wout[c];
    }
    #pragma unroll
    for (int off = 32; off > 0; off >>= 1) s += __shfl_down(s, off, 64);
    if (t == 0) out[gi] = s + bout[0];
}

// ---------------------------------------------------------------------------
extern "C" void kernel_launch(void* const* d_in, const int* in_sizes, int n_in,
                              void* d_out, int out_size, void* d_ws, size_t ws_size,
                              hipStream_t stream)
{
    const float* x      = (const float*)d_in[0];
    const int*   esrc   = (const int*)d_in[1];
    const int*   edst   = (const int*)d_in[2];
    const int*   batch  = (const int*)d_in[3];
    const float* Wrel0  = (const float*)d_in[4];
    const float* brel0  = (const float*)d_in[5];
    const float* Wroot0 = (const float*)d_in[6];
    const float* Wrel   = (const float*)d_in[7];
    const float* brel   = (const float*)d_in[8];
    const float* Wroot  = (const float*)d_in[9];
    const float* gamma  = (const float*)d_in[10];
    const float* beta   = (const float*)d_in[11];
    const float* Wh1    = (const float*)d_in[12];
    const float* bh1    = (const float*)d_in[13];
    const float* Wh2    = (const float*)d_in[14];
    const float* bh2    = (const float*)d_in[15];
    const float* Wout   = (const float*)d_in[16];
    const float* bout   = (const float*)d_in[17];
    float* out = (float*)d_out;

    const int N  = in_sizes[3];           // 100000
    const int E  = in_sizes[1];           // 400000
    const int K0 = in_sizes[0] / N;       // 32
    const int G  = out_size;              // 2000
    const int nBlocks = (N + 255) / 256;
    const float invN = 1.0f / (float)N;

    char* p = (char*)d_ws;
    auto carve = [&](size_t bytes) -> void* {
        void* r = (void*)p; p += (bytes + 255) & ~(size_t)255; return r;
    };
    ushort* bufa_h= (ushort*)carve((size_t)N * HDIM * 2);   // raw conv h (ping)
    ushort* bufb_h= (ushort*)carve((size_t)N * HDIM * 2);   // raw conv h (pong)
    ushort* xh    = (ushort*)carve((size_t)N * K0 * 2);     // layer0 input fp16
    ushort* gh    = (ushort*)carve((size_t)N * K0 * 2);     // layer0 gathered
    ushort* gsh   = (ushort*)carve((size_t)G * HDIM * 2);
    ushort* g1h   = (ushort*)carve((size_t)G * HDIM * 2);
    ushort* g2h   = (ushort*)carve((size_t)G * HDIM * 2);
    // deg + bnsums adjacent -> single memset
    int*    deg   = (int*)   carve((size_t)N * 4);
    float*  bnsums= (float*) carve(4 * 2 * HDIM * 4);
    size_t  zspan = (char*)(bnsums + 4 * 2 * HDIM) - (char*)deg;
    float*  degf  = (float*) carve((size_t)N * 4);
    int*    row_ptr=(int*)   carve((size_t)(N + 1) * 4);
    int*    cursor= (int*)   carve((size_t)N * 4);
    int*    col   = (int*)   carve((size_t)E * 4);
    int*    bsum  = (int*)   carve((size_t)nBlocks * 4);
    ushort* Wrel0f= (ushort*)carve((size_t)K0 * HDIM * 2);
    ushort* Wroot0f=(ushort*)carve((size_t)K0 * HDIM * 2);
    ushort* Wrelf = (ushort*)carve((size_t)3 * HDIM * HDIM * 2);
    ushort* Wrootf= (ushort*)carve((size_t)3 * HDIM * HDIM * 2);
    ushort* Wh1f  = (ushort*)carve((size_t)HDIM * HDIM * 2);
    ushort* Wh2f  = (ushort*)carve((size_t)HDIM * HDIM * 2);

    dim3 b256(256);
    const int eBlocks = (E + 255) / 256;
    const int gemmN = (N + 63) / 64;
    const int gemmG = (G + 63) / 64;

    float*  pbuf  = (float*) carve((size_t)gemmN * 2 * HDIM * 4);  // BN partials

    // ---- merged weight prep (1 launch)
    {
        PrepArgs a;
        int t0 = (K0 >> 5) * 12 * 64;        // 768
        int t1 = (HDIM >> 5) * 12 * 64;      // 4608
        a.src[0] = Wrel0;  a.dst[0] = Wrel0f;  a.K[0] = K0;
        a.src[1] = Wroot0; a.dst[1] = Wroot0f; a.K[1] = K0;
        a.src[2] = Wrel;   a.dst[2] = Wrelf;   a.K[2] = HDIM;
        a.src[3] = Wroot;  a.dst[3] = Wrootf;  a.K[3] = HDIM;
        a.src[4] = Wh1;    a.dst[4] = Wh1f;    a.K[4] = HDIM;
        a.src[5] = Wh2;    a.dst[5] = Wh2f;    a.K[5] = HDIM;
        a.off[0] = 0;
        a.off[1] = a.off[0] + t0;
        a.off[2] = a.off[1] + t0;
        a.off[3] = a.off[2] + 3 * t1;
        a.off[4] = a.off[3] + 3 * t1;
        a.off[5] = a.off[4] + t1;
        a.off[6] = a.off[5] + t1;
        prep_all_k<<<(a.off[6] + 255) / 256, b256, 0, stream>>>(a);
    }
    // x -> row-major fp16 [N][32]
    conv_half_k<<<((N * (K0 >> 3)) + 255) / 256, b256, 0, stream>>>(x, xh, N, K0);

    // ---- CSR build
    hipMemsetAsync(deg, 0, zspan, stream);   // zeros deg + bnsums
    hist_k<<<eBlocks, b256, 0, stream>>>(edst, deg, E);
    block_sum_k<<<nBlocks, b256, 0, stream>>>(deg, bsum, N);
    scan_bsum_k<<<1, dim3(512), 0, stream>>>(bsum, nBlocks);
    row_ptr_k<<<nBlocks, b256, 0, stream>>>(deg, bsum, row_ptr, cursor, degf, N, E);
    fill_k<<<eBlocks, b256, 0, stream>>>(esrc, edst, cursor, col, E);

    // ---- layer 0 (input x, no input BN): K=32 dual -> NKC=1; writes bufa
    gather_h_k<<<((N * (K0 >> 3)) + 255) / 256, b256, 0, stream>>>(
        xh, row_ptr, col, gh, N, K0);
    gemm_mfma_k<true, false, true, true, 1><<<gemmN, b256, 0, stream>>>(
        gh, Wrel0f, xh, Wroot0f, degf, brel0, bufa_h, pbuf, N, K0);
    bn_reduce_k<<<48, b256, 0, stream>>>(pbuf, bnsums, gemmN);

    // ---- layers 1..3: FUSED gather+BN+GEMM (512 thr), ping-pong bufa<->bufb
    ushort* rd = bufa_h;
    ushort* wr = bufb_h;
    for (int l = 1; l < 4; ++l) {
        const ushort* Wrf = Wrelf  + (size_t)(l - 1) * HDIM * HDIM;
        const ushort* Wtf = Wrootf + (size_t)(l - 1) * HDIM * HDIM;
        const float*  br  = brel   + (size_t)(l - 1) * HDIM;
        const float*  st  = bnsums + (size_t)(l - 1) * 2 * HDIM;
        const float*  gm  = gamma  + (size_t)(l - 1) * HDIM;
        const float*  bt  = beta   + (size_t)(l - 1) * HDIM;
        gemm_fused_k<<<gemmN, dim3(512), 0, stream>>>(
            rd, Wrf, Wtf, degf, br, st, gm, bt, invN,
            row_ptr, col, wr, pbuf, N);
        bn_reduce_k<<<48, b256, 0, stream>>>(pbuf, bnsums + l * 2 * HDIM, gemmN);
        ushort* tmp = rd; rd = wr; wr = tmp;
    }
    // after 3 layers: rd holds the final raw h (bufb)

    // ---- fused final BN + mean pool -> fp16 row-major head input
    pool_bn_k<<<G, dim3(192), 0, stream>>>(
        rd, bnsums + 3 * 2 * HDIM, gamma + 3 * HDIM, beta + 3 * HDIM,
        invN, batch, gsh, G, N);

    // ---- head MLP (MFMA path, row-major fp16 end-to-end; K=192 -> NKC=6)
    gemm_mfma_k<false, true, false, false, 6><<<gemmG, b256, 0, stream>>>(
        gsh, Wh1f, nullptr, nullptr, nullptr, bh1, g1h, nullptr, G, HDIM);
    gemm_mfma_k<false, false, false, false, 6><<<gemmG, b256, 0, stream>>>(
        g1h, Wh2f, nullptr, nullptr, nullptr, bh2, g2h, nullptr, G, HDIM);
    out_dot_k<<<G, dim3(64), 0, stream>>>(g2h, Wout, bout, out, G);
}